// Round 6
// baseline (661.437 us; speedup 1.0000x reference)
//
#include <hip/hip_runtime.h>
#include <hip/hip_fp16.h>

#define N_S 32
#define N_V 16
#define NB 8
#define HH 64
#define NIR 112
#define ROW 240   // 48 scalar + 64*3 vector output channels
#define MROW 120  // sorted mix row: 112 fp16 mix + {u0,u1,u2 fp32, sender int}

typedef _Float16 half8 __attribute__((ext_vector_type(8)));
typedef float f32x4 __attribute__((ext_vector_type(4)));

__device__ __forceinline__ float swishf(float x) {
  return x / (1.f + __expf(-x));
}

struct ChanDesc { int path, off, mixI, i; };

__device__ __forceinline__ void mkDesc(int t, ChanDesc& d) {
  if (t < 32) { d.path = 0; d.off = t; d.mixI = t; d.i = 0; }
  else if (t < 48) { d.path = 1; d.off = 3 * (t - 32); d.mixI = t; d.i = 0; }
  else if (t < ROW) {
    int q = t - 48, c = q / 3, i = q - 3 * c;
    d.mixI = 48 + c;
    if (c < 16) { d.path = 2; d.off = q; d.i = 0; }
    else if (c < 48) { d.path = 3; d.off = c - 16; d.i = i; }
    else { d.path = 4; d.off = 3 * (c - 48); d.i = i; }
  } else { d.path = -1; d.off = 0; d.mixI = 0; d.i = 0; }
}

__device__ __forceinline__ float evalChan(const ChanDesc& d,
                                          const float* __restrict__ srow,
                                          const float* __restrict__ vrow,
                                          float mix, float u0, float u1, float u2) {
  if (d.path < 0) return 0.f;
  if (d.path == 0) return srow[d.off] * mix;
  if (d.path == 2) return vrow[d.off] * mix;
  float uo = d.i == 0 ? u0 : (d.i == 1 ? u1 : u2);
  if (d.path == 3) return srow[d.off] * uo * mix;
  float dd = vrow[d.off] * u0 + vrow[d.off + 1] * u1 + vrow[d.off + 2] * u2;
  if (d.path == 1) return dd * mix;
  return 1.22474487139f * (uo * dd - vrow[d.off + d.i] * 0.33333333333f) * mix;
}

__device__ __forceinline__ float evalChan16(const ChanDesc& d,
                                            const _Float16* __restrict__ srow,
                                            const _Float16* __restrict__ vrow,
                                            float mix, float u0, float u1, float u2) {
  if (d.path == 0) return (float)srow[d.off] * mix;
  if (d.path == 2) return (float)vrow[d.off] * mix;
  float uo = d.i == 0 ? u0 : (d.i == 1 ? u1 : u2);
  if (d.path == 3) return (float)srow[d.off] * uo * mix;
  float dd = (float)vrow[d.off] * u0 + (float)vrow[d.off + 1] * u1 + (float)vrow[d.off + 2] * u2;
  if (d.path == 1) return dd * mix;
  return 1.22474487139f * (uo * dd - (float)vrow[d.off + d.i] * 0.33333333333f) * mix;
}

__device__ __forceinline__ void radialEmb(float x, float y, float z, bool valid,
                                          float* emb, float* u0, float* u1, float* u2) {
  float r2 = x * x + y * y + z * z;
  float r = sqrtf(r2);
  float invr = 1.f / fmaxf(r, 1e-12f);
  *u0 = x * invr; *u1 = y * invr; *u2 = z * invr;
  float env = 0.f;
  if (r < 1.f) {
    float r3 = r * r2;
    float r6 = r3 * r3;
    env = 1.f + r6 * (-28.f + (48.f - 21.f * r) * r);
  }
  float coef = 1.41421356237f * invr * env;
  if (!valid || r == 0.f) coef = 0.f;
  float ph = 3.14159265358979323846f * r;
  float s1 = __sinf(ph), c1 = __cosf(ph);
  float twc = 2.f * c1;
  float sp = 0.f, sc = s1;
#pragma unroll
  for (int n = 0; n < NB; ++n) {  // sin(pi*n*r) via Chebyshev recurrence
    emb[n] = coef * sc;
    float sn = twc * sc - sp;
    sp = sc;
    sc = sn;
  }
}

// ============================ sort ============================

__global__ __launch_bounds__(256) void hist_kernel(const int* __restrict__ rcv,
                                                   int* __restrict__ hist, int E) {
  int e = blockIdx.x * 256 + threadIdx.x;
  if (e < E) atomicAdd(&hist[rcv[e]], 1);
}

__global__ __launch_bounds__(256) void scan1_kernel(const int* __restrict__ hist,
                                                    int* __restrict__ scanTmp,
                                                    int* __restrict__ bsum, int N) {
  __shared__ int sh[256];
  int t = threadIdx.x;
  int i = blockIdx.x * 256 + t;
  sh[t] = (i < N) ? hist[i] : 0;
  __syncthreads();
#pragma unroll
  for (int off = 1; off < 256; off <<= 1) {
    int x = (t >= off) ? sh[t - off] : 0;
    __syncthreads();
    sh[t] += x;
    __syncthreads();
  }
  if (i < N) scanTmp[i] = sh[t];
  if (t == 255) bsum[blockIdx.x] = sh[255];
}

__global__ __launch_bounds__(256) void scan2_kernel(int* __restrict__ bsum, int nb) {
  __shared__ int sh[256];
  int t = threadIdx.x;
  sh[t] = (t < nb) ? bsum[t] : 0;
  __syncthreads();
#pragma unroll
  for (int off = 1; off < 256; off <<= 1) {
    int x = (t >= off) ? sh[t - off] : 0;
    __syncthreads();
    sh[t] += x;
    __syncthreads();
  }
  int excl = (t == 0) ? 0 : sh[t - 1];
  if (t < nb) bsum[t] = excl;
}

__global__ __launch_bounds__(256) void scan3_kernel(const int* __restrict__ scanTmp,
                                                    const int* __restrict__ bsum,
                                                    const int* __restrict__ hist,
                                                    int* __restrict__ offs,
                                                    int* __restrict__ cursor, int N) {
  int i = blockIdx.x * 256 + threadIdx.x;
  if (i < N) {
    int incl = scanTmp[i] + bsum[blockIdx.x];
    offs[i + 1] = incl;
    cursor[i] = incl - hist[i];
    if (i == 0) offs[0] = 0;
  }
}

__global__ __launch_bounds__(256) void reorder_kernel(const int* __restrict__ rcv,
                                                      int* __restrict__ cursor,
                                                      int* __restrict__ sortedE, int E) {
  int e = blockIdx.x * 256 + threadIdx.x;
  if (e < E) {
    int pos = atomicAdd(&cursor[rcv[e]], 1);
    sortedE[pos] = e;
  }
}

__global__ __launch_bounds__(256) void reorderInv_kernel(const int* __restrict__ rcv,
                                                         int* __restrict__ cursor,
                                                         int* __restrict__ invPos, int E) {
  int e = blockIdx.x * 256 + threadIdx.x;
  if (e < E) {
    int pos = atomicAdd(&cursor[rcv[e]], 1);
    invPos[e] = pos;
  }
}

// ==================== weight / node dtype conversion ====================

__global__ __launch_bounds__(256) void wconv2_kernel(const float* __restrict__ W1,
                                                     const float* __restrict__ W2,
                                                     _Float16* __restrict__ W1T,
                                                     _Float16* __restrict__ W2T) {
  int i = blockIdx.x * 256 + threadIdx.x;
  if (i < 4096) {
    int k = i >> 6, n = i & 63;
    W1T[n * 64 + k] = (_Float16)(W1[k * 64 + n] * 0.125f);
  } else if (i < 4096 + 7168) {
    int j = i - 4096;
    int k = j / 112, n = j - k * 112;
    W2T[n * 64 + k] = (_Float16)(W2[k * 112 + n] * 0.125f);
  }
}

__global__ __launch_bounds__(256) void nodeconv_kernel(const float* __restrict__ ns,
                                                       const float* __restrict__ nv,
                                                       _Float16* __restrict__ s16,
                                                       _Float16* __restrict__ v16, int N) {
  int i = blockIdx.x * 256 + threadIdx.x;
  int ts = N * N_S;
  int tv = N * N_V * 3;
  if (i < ts) s16[i] = (_Float16)ns[i];
  else if (i < ts + tv) v16[i - ts] = (_Float16)nv[i - ts];
}

// ==================== MFMA radial MLP -> receiver-sorted rows ====================
// Block = 4 waves; wave owns 64 edges + private 9216-B LDS slice (no barriers).
// Row layout in hb per edge: halves [0..63] h1/h2/stage, [64..71] aux {u fp32 x3, sender}.
// Output row (MROW=120 halves): [0..111] mix fp16, [112..119] aux — written to invPos[e].
__global__ __launch_bounds__(256, 4) void mlp_mfma_sorted_kernel(
    const float* __restrict__ vec,
    const float* __restrict__ W0,
    const _Float16* __restrict__ W1T,   // [n=64][k=64], *0.125
    const _Float16* __restrict__ W2T,   // [n=112][k=64], *0.125
    const int* __restrict__ senders,
    const int* __restrict__ invPos,
    _Float16* __restrict__ mixS,        // [E][MROW]
    int E) {
  __shared__ __align__(16) _Float16 hbuf[4 * 64 * 72];
  const int lane = threadIdx.x & 63;
  const int wave = threadIdx.x >> 6;
  const int gbase = blockIdx.x * 256 + wave * 64;
  _Float16* hb = hbuf + wave * (64 * 72);

  const int m15 = lane & 15;
  const int q = lane >> 4;

  // ---- phase 1: lane = edge; emb -> h1 -> LDS row; aux -> pad halves ----
  {
    int e = gbase + lane;
    bool valid = e < E;
    float x = 0.f, y = 0.f, z = 0.f;
    int snd = 0;
    if (valid) {
      const float* vp = vec + 3 * (size_t)e;
      x = vp[0]; y = vp[1]; z = vp[2];
      snd = senders[e];
    }
    float emb[NB], u0, u1, u2;
    radialEmb(x, y, z, valid, emb, &u0, &u1, &u2);
    for (int kg = 0; kg < 8; ++kg) {
      half8 pk;
#pragma unroll
      for (int kk = 0; kk < 8; ++kk) {
        int k = kg * 8 + kk;
        float a = 0.f;
#pragma unroll
        for (int n = 0; n < NB; ++n) a = fmaf(emb[n], W0[n * HH + k], a);
        pk[kk] = (_Float16)swishf(a * 0.35355339059f);
      }
      *(half8*)(hb + lane * 72 + kg * 8) = pk;
    }
    float* auxp = (float*)(hb + lane * 72 + 64);
    auxp[0] = u0; auxp[1] = u1; auxp[2] = u2;
    ((int*)auxp)[3] = snd;
  }

  // ---- W1 B-fragments ----
  half8 bW1[4][2];
#pragma unroll
  for (int nt = 0; nt < 4; ++nt)
#pragma unroll
    for (int q2 = 0; q2 < 2; ++q2)
      bW1[nt][q2] = *(const half8*)(W1T + (nt * 16 + m15) * 64 + q2 * 32 + q * 8);

  // ---- layer 1: MFMA, swish, write h2 in place ----
#pragma unroll
  for (int t = 0; t < 4; ++t) {
    half8 a0 = *(const half8*)(hb + (t * 16 + m15) * 72 + q * 8);
    half8 a1 = *(const half8*)(hb + (t * 16 + m15) * 72 + 32 + q * 8);
#pragma unroll
    for (int nt = 0; nt < 4; ++nt) {
      f32x4 d = {0.f, 0.f, 0.f, 0.f};
      d = __builtin_amdgcn_mfma_f32_16x16x32_f16(a0, bW1[nt][0], d, 0, 0, 0);
      d = __builtin_amdgcn_mfma_f32_16x16x32_f16(a1, bW1[nt][1], d, 0, 0, 0);
#pragma unroll
      for (int r = 0; r < 4; ++r)
        hb[(t * 16 + q * 4 + r) * 72 + nt * 16 + m15] = (_Float16)swishf(d[r]);
    }
  }

  // ---- layer 2 A-fragments in regs ----
  half8 A2[4][2];
#pragma unroll
  for (int t = 0; t < 4; ++t)
#pragma unroll
    for (int q2 = 0; q2 < 2; ++q2)
      A2[t][q2] = *(const half8*)(hb + (t * 16 + m15) * 72 + q2 * 32 + q * 8);

  // ---- layer 2 half 0: N-tiles 0..3 (ch 0..63) ----
  for (int nl = 0; nl < 4; ++nl) {
    half8 b0 = *(const half8*)(W2T + (nl * 16 + m15) * 64 + q * 8);
    half8 b1 = *(const half8*)(W2T + (nl * 16 + m15) * 64 + 32 + q * 8);
#pragma unroll
    for (int t = 0; t < 4; ++t) {
      f32x4 d = {0.f, 0.f, 0.f, 0.f};
      d = __builtin_amdgcn_mfma_f32_16x16x32_f16(A2[t][0], b0, d, 0, 0, 0);
      d = __builtin_amdgcn_mfma_f32_16x16x32_f16(A2[t][1], b1, d, 0, 0, 0);
#pragma unroll
      for (int r = 0; r < 4; ++r)
        hb[(t * 16 + q * 4 + r) * 72 + nl * 16 + m15] = (_Float16)d[r];
    }
  }
  // store ch 0..63 to sorted rows (8 chunks/edge, 128-B contiguous runs)
  for (int it = 0; it < 8; ++it) {
    int c = it * 64 + lane;
    int el = c >> 3, p = c & 7;
    int e = gbase + el;
    half8 v = *(const half8*)(hb + el * 72 + p * 8);
    if (e < E) {
      int pos = invPos[e];
      *(half8*)(mixS + (size_t)pos * MROW + p * 8) = v;
    }
  }

  // ---- layer 2 half 1: N-tiles 4..6 (ch 64..111) ----
  for (int nl = 0; nl < 3; ++nl) {
    int ntg = 4 + nl;
    half8 b0 = *(const half8*)(W2T + (ntg * 16 + m15) * 64 + q * 8);
    half8 b1 = *(const half8*)(W2T + (ntg * 16 + m15) * 64 + 32 + q * 8);
#pragma unroll
    for (int t = 0; t < 4; ++t) {
      f32x4 d = {0.f, 0.f, 0.f, 0.f};
      d = __builtin_amdgcn_mfma_f32_16x16x32_f16(A2[t][0], b0, d, 0, 0, 0);
      d = __builtin_amdgcn_mfma_f32_16x16x32_f16(A2[t][1], b1, d, 0, 0, 0);
#pragma unroll
      for (int r = 0; r < 4; ++r)
        hb[(t * 16 + q * 4 + r) * 72 + nl * 16 + m15] = (_Float16)d[r];
    }
  }
  // store ch 64..111 + aux (7 chunks/edge, 112-B contiguous runs)
  for (int it = 0; it < 7; ++it) {
    int c = it * 64 + lane;
    int el = (int)(((unsigned)c * 9363u) >> 16);  // c/7 for c<448
    int p = c - el * 7;
    int e = gbase + el;
    half8 v = *(const half8*)(hb + el * 72 + (p < 6 ? p * 8 : 64));
    if (e < E) {
      int pos = invPos[e];
      *(half8*)(mixS + (size_t)pos * MROW + 64 + p * 8) = v;  // p==6 -> offset 112 (aux)
    }
  }
}

// ==================== sorted gather: streaming rows, no indirection ====================

__device__ __forceinline__ void gstep(int i, const _Float16* __restrict__ mixS,
                                      const _Float16* __restrict__ s16,
                                      const _Float16* __restrict__ v16,
                                      const ChanDesc* __restrict__ d, float* __restrict__ acc) {
  const _Float16* row = mixS + (size_t)i * MROW;
  float4 aux = *(const float4*)(const void*)(row + 112);  // uniform -> s_load
  int snd = __float_as_int(aux.w);
  const _Float16* srow = s16 + (size_t)snd * N_S;
  const _Float16* vrow = v16 + (size_t)snd * (N_V * 3);
#pragma unroll
  for (int tb = 0; tb < 4; ++tb) {
    if (d[tb].path >= 0) {
      float m = (float)row[d[tb].mixI];
      acc[tb] += evalChan16(d[tb], srow, vrow, m, aux.x, aux.y, aux.z);
    }
  }
}

__global__ __launch_bounds__(256) void gather_sorted_kernel(
    const _Float16* __restrict__ mixS,
    const _Float16* __restrict__ s16,
    const _Float16* __restrict__ v16,
    const int* __restrict__ offs,
    float* __restrict__ out, int N) {
  int wid = blockIdx.x * 4 + (threadIdx.x >> 6);
  int lane = threadIdx.x & 63;
  if (wid >= N) return;

  ChanDesc d[4];
#pragma unroll
  for (int tb = 0; tb < 4; ++tb) mkDesc(tb * 64 + lane, d[tb]);

  float acc[4] = {0.f, 0.f, 0.f, 0.f};
  int s0 = __builtin_amdgcn_readfirstlane(offs[wid]);
  int s1 = __builtin_amdgcn_readfirstlane(offs[wid + 1]);

  int i = s0;
  for (; i + 2 <= s1; i += 2) {  // 2x unroll: overlap the two edges' load chains
    gstep(i, mixS, s16, v16, d, acc);
    gstep(i + 1, mixS, s16, v16, d, acc);
  }
  if (i < s1) gstep(i, mixS, s16, v16, d, acc);

  float* orow = out + (size_t)wid * ROW;
#pragma unroll
  for (int tb = 0; tb < 4; ++tb) {
    int t = tb * 64 + lane;
    if (t < ROW) orow[t] = 0.25f * acc[tb];
  }
}

// ==================== tier B: round-5 kernels (edge-ordered mix) ====================

__global__ __launch_bounds__(256, 4) void mlp_mfma_kernel(
    const float* __restrict__ vec,
    const float* __restrict__ W0,
    const _Float16* __restrict__ W1T,
    const _Float16* __restrict__ W2T,
    __half* __restrict__ mixOut, int E) {
  __shared__ __align__(16) _Float16 hbuf[4 * 64 * 72];
  const int lane = threadIdx.x & 63;
  const int wave = threadIdx.x >> 6;
  const int gbase = blockIdx.x * 256 + wave * 64;
  _Float16* hb = hbuf + wave * (64 * 72);
  const int m15 = lane & 15;
  const int q = lane >> 4;

  {
    int e = gbase + lane;
    bool valid = e < E;
    float x = 0.f, y = 0.f, z = 0.f;
    if (valid) {
      const float* vp = vec + 3 * (size_t)e;
      x = vp[0]; y = vp[1]; z = vp[2];
    }
    float emb[NB], u0, u1, u2;
    radialEmb(x, y, z, valid, emb, &u0, &u1, &u2);
    for (int kg = 0; kg < 8; ++kg) {
      half8 pk;
#pragma unroll
      for (int kk = 0; kk < 8; ++kk) {
        int k = kg * 8 + kk;
        float a = 0.f;
#pragma unroll
        for (int n = 0; n < NB; ++n) a = fmaf(emb[n], W0[n * HH + k], a);
        pk[kk] = (_Float16)swishf(a * 0.35355339059f);
      }
      *(half8*)(hb + lane * 72 + kg * 8) = pk;
    }
  }

  half8 bW1[4][2];
#pragma unroll
  for (int nt = 0; nt < 4; ++nt)
#pragma unroll
    for (int q2 = 0; q2 < 2; ++q2)
      bW1[nt][q2] = *(const half8*)(W1T + (nt * 16 + m15) * 64 + q2 * 32 + q * 8);

#pragma unroll
  for (int t = 0; t < 4; ++t) {
    half8 a0 = *(const half8*)(hb + (t * 16 + m15) * 72 + q * 8);
    half8 a1 = *(const half8*)(hb + (t * 16 + m15) * 72 + 32 + q * 8);
#pragma unroll
    for (int nt = 0; nt < 4; ++nt) {
      f32x4 d = {0.f, 0.f, 0.f, 0.f};
      d = __builtin_amdgcn_mfma_f32_16x16x32_f16(a0, bW1[nt][0], d, 0, 0, 0);
      d = __builtin_amdgcn_mfma_f32_16x16x32_f16(a1, bW1[nt][1], d, 0, 0, 0);
#pragma unroll
      for (int r = 0; r < 4; ++r)
        hb[(t * 16 + q * 4 + r) * 72 + nt * 16 + m15] = (_Float16)swishf(d[r]);
    }
  }

  half8 A2[4][2];
#pragma unroll
  for (int t = 0; t < 4; ++t)
#pragma unroll
    for (int q2 = 0; q2 < 2; ++q2)
      A2[t][q2] = *(const half8*)(hb + (t * 16 + m15) * 72 + q2 * 32 + q * 8);

  for (int hf = 0; hf < 2; ++hf) {
    const int ntCount = hf ? 3 : 4;
    for (int nl = 0; nl < ntCount; ++nl) {
      int ntg = hf * 4 + nl;
      half8 b0 = *(const half8*)(W2T + (ntg * 16 + m15) * 64 + q * 8);
      half8 b1 = *(const half8*)(W2T + (ntg * 16 + m15) * 64 + 32 + q * 8);
#pragma unroll
      for (int t = 0; t < 4; ++t) {
        f32x4 d = {0.f, 0.f, 0.f, 0.f};
        d = __builtin_amdgcn_mfma_f32_16x16x32_f16(A2[t][0], b0, d, 0, 0, 0);
        d = __builtin_amdgcn_mfma_f32_16x16x32_f16(A2[t][1], b1, d, 0, 0, 0);
#pragma unroll
        for (int r = 0; r < 4; ++r)
          hb[(t * 16 + q * 4 + r) * 72 + nl * 16 + m15] = (_Float16)d[r];
      }
    }
    if (hf == 0) {
      for (int it = 0; it < 8; ++it) {
        int c = it * 64 + lane;
        int el = c >> 3, p = c & 7;
        int e = gbase + el;
        half8 v = *(const half8*)(hb + el * 72 + p * 8);
        if (e < E) *(half8*)((_Float16*)mixOut + (size_t)e * NIR + p * 8) = v;
      }
    } else {
      for (int it = 0; it < 6; ++it) {
        int c = it * 64 + lane;
        int el = (int)(((unsigned)c * 43691u) >> 18);
        int p = c - el * 6;
        int e = gbase + el;
        half8 v = *(const half8*)(hb + el * 72 + p * 8);
        if (e < E) *(half8*)((_Float16*)mixOut + (size_t)e * NIR + 64 + p * 8) = v;
      }
    }
  }
}

__global__ __launch_bounds__(256) void gather_kernel(
    const float* __restrict__ vec,
    const float* __restrict__ nodes_s,
    const float* __restrict__ nodes_v,
    const int* __restrict__ senders,
    const int* __restrict__ offs,
    const int* __restrict__ sortedE,
    const __half* __restrict__ mix,
    float* __restrict__ out, int N) {
  int wid = blockIdx.x * 4 + (threadIdx.x >> 6);
  int lane = threadIdx.x & 63;
  if (wid >= N) return;

  ChanDesc d[4];
#pragma unroll
  for (int tb = 0; tb < 4; ++tb) mkDesc(tb * 64 + lane, d[tb]);

  float acc[4] = {0.f, 0.f, 0.f, 0.f};
  int s0 = offs[wid], s1 = offs[wid + 1];

  for (int i = s0; i < s1; ++i) {
    int e = __builtin_amdgcn_readfirstlane(sortedE[i]);
    int snd = __builtin_amdgcn_readfirstlane(senders[e]);
    const float* vp = vec + 3 * (size_t)e;
    float x = vp[0], y = vp[1], z = vp[2];
    float r = sqrtf(x * x + y * y + z * z);
    float invr = 1.f / fmaxf(r, 1e-12f);
    float u0 = x * invr, u1 = y * invr, u2 = z * invr;
    const float* srow = nodes_s + (size_t)snd * N_S;
    const float* vrow = nodes_v + (size_t)snd * (N_V * 3);
    const __half* mrow = mix + (size_t)e * NIR;
#pragma unroll
    for (int tb = 0; tb < 4; ++tb) {
      if (d[tb].path >= 0) {
        float m = __half2float(mrow[d[tb].mixI]);
        acc[tb] += evalChan(d[tb], srow, vrow, m, u0, u1, u2);
      }
    }
  }

  float* orow = out + (size_t)wid * ROW;
#pragma unroll
  for (int tb = 0; tb < 4; ++tb) {
    int t = tb * 64 + lane;
    if (t < ROW) orow[t] = 0.25f * acc[tb];
  }
}

// ==================== tier C fallback: atomic edge kernel ====================

__global__ __launch_bounds__(64) void edge_kernel(
    const float* __restrict__ vec,
    const float* __restrict__ nodes_s,
    const float* __restrict__ nodes_v,
    const int* __restrict__ senders,
    const int* __restrict__ receivers,
    const float* __restrict__ W0f,
    const float* __restrict__ W1f,
    const float* __restrict__ W2f,
    float* __restrict__ out, int E) {
  __shared__ float hLds[HH * 64];
  __shared__ float uLds[64 * 3];
  __shared__ int sLds[64];
  __shared__ int rLds[64];
  __half* mixLds = reinterpret_cast<__half*>(hLds);

  const int lane = threadIdx.x;
  const int base = blockIdx.x * 64;
  const int eg = base + lane;
  const bool valid = eg < E;

  float emb[NB];
  {
    float x = 0.f, y = 0.f, z = 0.f;
    int snd = 0, rcv = 0;
    if (valid) {
      const float* vp = vec + 3 * (size_t)eg;
      x = vp[0]; y = vp[1]; z = vp[2];
      snd = senders[eg];
      rcv = receivers[eg];
    }
    float u0, u1, u2;
    radialEmb(x, y, z, valid, emb, &u0, &u1, &u2);
    uLds[lane * 3 + 0] = u0;
    uLds[lane * 3 + 1] = u1;
    uLds[lane * 3 + 2] = u2;
    sLds[lane] = snd;
    rLds[lane] = rcv;
  }

  for (int j0 = 0; j0 < HH; j0 += 8) {
    float a[8];
#pragma unroll
    for (int jj = 0; jj < 8; ++jj) a[jj] = 0.f;
#pragma unroll
    for (int k = 0; k < NB; ++k) {
      const float* wrow = W0f + k * HH + j0;
      float ek = emb[k];
#pragma unroll
      for (int jj = 0; jj < 8; ++jj) a[jj] = fmaf(ek, wrow[jj], a[jj]);
    }
#pragma unroll
    for (int jj = 0; jj < 8; ++jj)
      hLds[(j0 + jj) * 64 + lane] = swishf(a[jj] * 0.35355339059f);
  }
  __syncthreads();

  float h2[HH];
#pragma unroll
  for (int j = 0; j < HH; ++j) h2[j] = 0.f;
  for (int k = 0; k < HH; ++k) {
    float hk = hLds[k * 64 + lane];
    const float* wrow = W1f + k * HH;
#pragma unroll
    for (int j = 0; j < HH; ++j) h2[j] = fmaf(hk, wrow[j], h2[j]);
  }
#pragma unroll
  for (int j = 0; j < HH; ++j) h2[j] = swishf(h2[j] * 0.125f);
  __syncthreads();

  for (int m0 = 0; m0 < NIR; m0 += 4) {
    float a0 = 0.f, a1 = 0.f, a2 = 0.f, a3 = 0.f;
#pragma unroll
    for (int k = 0; k < HH; ++k) {
      const float* wrow = W2f + k * NIR + m0;
      float hk = h2[k];
      a0 = fmaf(hk, wrow[0], a0);
      a1 = fmaf(hk, wrow[1], a1);
      a2 = fmaf(hk, wrow[2], a2);
      a3 = fmaf(hk, wrow[3], a3);
    }
    mixLds[lane * NIR + m0 + 0] = __float2half_rn(a0 * 0.125f);
    mixLds[lane * NIR + m0 + 1] = __float2half_rn(a1 * 0.125f);
    mixLds[lane * NIR + m0 + 2] = __float2half_rn(a2 * 0.125f);
    mixLds[lane * NIR + m0 + 3] = __float2half_rn(a3 * 0.125f);
  }
  __syncthreads();

  ChanDesc d[4];
#pragma unroll
  for (int tb = 0; tb < 4; ++tb) mkDesc(tb * 64 + lane, d[tb]);

  const int cnt = min(64, E - base);
  for (int e = 0; e < cnt; ++e) {
    int snd = sLds[e], rcv = rLds[e];
    float u0 = uLds[e * 3 + 0], u1 = uLds[e * 3 + 1], u2 = uLds[e * 3 + 2];
    const float* srow = nodes_s + (size_t)snd * N_S;
    const float* vrow = nodes_v + (size_t)snd * (N_V * 3);
    const __half* mrow = mixLds + e * NIR;
    float* orow = out + (size_t)rcv * ROW;
#pragma unroll
    for (int tb = 0; tb < 4; ++tb) {
      if (d[tb].path >= 0) {
        float m = __half2float(mrow[d[tb].mixI]);
        float val = evalChan(d[tb], srow, vrow, m, u0, u1, u2);
        unsafeAtomicAdd(orow + tb * 64 + lane, 0.25f * val);
      }
    }
  }
}

// ===============================================================================

extern "C" void kernel_launch(void* const* d_in, const int* in_sizes, int n_in,
                              void* d_out, int out_size, void* d_ws, size_t ws_size,
                              hipStream_t stream) {
  const float* vec = (const float*)d_in[0];
  const float* ns = (const float*)d_in[1];
  const float* nv = (const float*)d_in[2];
  const float* w0 = (const float*)d_in[3];
  const float* w1 = (const float*)d_in[4];
  const float* w2 = (const float*)d_in[5];
  const int* snd = (const int*)d_in[6];
  const int* rcv = (const int*)d_in[7];
  float* out = (float*)d_out;

  const int E = in_sizes[6];
  const int N = in_sizes[1] / N_S;
  const int nb = (N + 255) / 256;
  const int eb = (E + 255) / 256;

  // ---- tier A layout: sorted mix rows + fp16 nodes ----
  {
    char* p = (char*)d_ws;
    _Float16* mixS = (_Float16*)p; p += (size_t)E * MROW * sizeof(_Float16);
    int* hist = (int*)p;           p += (size_t)N * 4;
    int* scanTmp = (int*)p;        p += (size_t)N * 4;
    int* offs = (int*)p;           p += ((size_t)N + 1) * 4;
    int* cursor = (int*)p;         p += (size_t)N * 4;
    int* bsum = (int*)p;           p += 256 * 4;
    int* invPos = (int*)p;         p += (size_t)E * 4;
    p = (char*)(((uintptr_t)p + 15) & ~(uintptr_t)15);
    _Float16* W1T = (_Float16*)p;  p += 4096 * sizeof(_Float16);
    _Float16* W2T = (_Float16*)p;  p += 7168 * sizeof(_Float16);
    _Float16* s16 = (_Float16*)p;  p += (size_t)N * N_S * sizeof(_Float16);
    _Float16* v16 = (_Float16*)p;  p += (size_t)N * N_V * 3 * sizeof(_Float16);
    size_t needA = (size_t)(p - (char*)d_ws);

    if (needA <= ws_size && nb <= 256) {
      hipMemsetAsync(hist, 0, (size_t)N * 4, stream);
      hist_kernel<<<eb, 256, 0, stream>>>(rcv, hist, E);
      scan1_kernel<<<nb, 256, 0, stream>>>(hist, scanTmp, bsum, N);
      scan2_kernel<<<1, 256, 0, stream>>>(bsum, nb);
      scan3_kernel<<<nb, 256, 0, stream>>>(scanTmp, bsum, hist, offs, cursor, N);
      reorderInv_kernel<<<eb, 256, 0, stream>>>(rcv, cursor, invPos, E);
      wconv2_kernel<<<44, 256, 0, stream>>>(w1, w2, W1T, W2T);
      nodeconv_kernel<<<(N * 80 + 255) / 256, 256, 0, stream>>>(ns, nv, s16, v16, N);
      mlp_mfma_sorted_kernel<<<eb, 256, 0, stream>>>(vec, w0, W1T, W2T, snd, invPos, mixS, E);
      gather_sorted_kernel<<<(N + 3) / 4, 256, 0, stream>>>(mixS, s16, v16, offs, out, N);
      return;
    }
  }

  // ---- tier B layout: round-5 path ----
  {
    char* p = (char*)d_ws;
    __half* mixW = (__half*)p;     p += (size_t)E * NIR * sizeof(__half);
    int* hist = (int*)p;           p += (size_t)N * 4;
    int* scanTmp = (int*)p;        p += (size_t)N * 4;
    int* offs = (int*)p;           p += ((size_t)N + 1) * 4;
    int* cursor = (int*)p;         p += (size_t)N * 4;
    int* bsum = (int*)p;           p += 256 * 4;
    int* sortedE = (int*)p;        p += (size_t)E * 4;
    p = (char*)(((uintptr_t)p + 15) & ~(uintptr_t)15);
    _Float16* W1T = (_Float16*)p;  p += 4096 * sizeof(_Float16);
    _Float16* W2T = (_Float16*)p;  p += 7168 * sizeof(_Float16);
    size_t needB = (size_t)(p - (char*)d_ws);

    if (needB <= ws_size && nb <= 256) {
      hipMemsetAsync(hist, 0, (size_t)N * 4, stream);
      hist_kernel<<<eb, 256, 0, stream>>>(rcv, hist, E);
      scan1_kernel<<<nb, 256, 0, stream>>>(hist, scanTmp, bsum, N);
      scan2_kernel<<<1, 256, 0, stream>>>(bsum, nb);
      scan3_kernel<<<nb, 256, 0, stream>>>(scanTmp, bsum, hist, offs, cursor, N);
      reorder_kernel<<<eb, 256, 0, stream>>>(rcv, cursor, sortedE, E);
      wconv2_kernel<<<44, 256, 0, stream>>>(w1, w2, W1T, W2T);
      mlp_mfma_kernel<<<eb, 256, 0, stream>>>(vec, w0, W1T, W2T, mixW, E);
      gather_kernel<<<(N + 3) / 4, 256, 0, stream>>>(vec, ns, nv, snd, offs, sortedE, mixW, out, N);
      return;
    }
  }

  // ---- tier C: atomic fallback ----
  hipMemsetAsync(d_out, 0, (size_t)out_size * sizeof(float), stream);
  edge_kernel<<<(E + 63) / 64, 64, 0, stream>>>(vec, ns, nv, snd, rcv, w0, w1, w2, out, E);
}

// Round 7
// 561.726 us; speedup vs baseline: 1.1775x; 1.1775x over previous
//
#include <hip/hip_runtime.h>
#include <hip/hip_fp16.h>

#define N_S 32
#define N_V 16
#define NB 8
#define HH 64
#define NIR 112
#define ROW 240   // 48 scalar + 64*3 vector output channels
#define MROW 120  // sorted mix row: 112 fp16 mix + {u0,u1,u2 fp32, sender int}
#define GCAP 64   // edges staged per gather chunk

typedef _Float16 half8 __attribute__((ext_vector_type(8)));
typedef float f32x4 __attribute__((ext_vector_type(4)));

__device__ __forceinline__ float swishf(float x) {
  return x / (1.f + __expf(-x));
}

struct ChanDesc { int path, off, mixI, i; };

__device__ __forceinline__ void mkDesc(int t, ChanDesc& d) {
  if (t < 32) { d.path = 0; d.off = t; d.mixI = t; d.i = 0; }
  else if (t < 48) { d.path = 1; d.off = 3 * (t - 32); d.mixI = t; d.i = 0; }
  else if (t < ROW) {
    int q = t - 48, c = q / 3, i = q - 3 * c;
    d.mixI = 48 + c;
    if (c < 16) { d.path = 2; d.off = q; d.i = 0; }
    else if (c < 48) { d.path = 3; d.off = c - 16; d.i = i; }
    else { d.path = 4; d.off = 3 * (c - 48); d.i = i; }
  } else { d.path = -1; d.off = 0; d.mixI = 0; d.i = 0; }
}

__device__ __forceinline__ float evalChan(const ChanDesc& d,
                                          const float* __restrict__ srow,
                                          const float* __restrict__ vrow,
                                          float mix, float u0, float u1, float u2) {
  if (d.path < 0) return 0.f;
  if (d.path == 0) return srow[d.off] * mix;
  if (d.path == 2) return vrow[d.off] * mix;
  float uo = d.i == 0 ? u0 : (d.i == 1 ? u1 : u2);
  if (d.path == 3) return srow[d.off] * uo * mix;
  float dd = vrow[d.off] * u0 + vrow[d.off + 1] * u1 + vrow[d.off + 2] * u2;
  if (d.path == 1) return dd * mix;
  return 1.22474487139f * (uo * dd - vrow[d.off + d.i] * 0.33333333333f) * mix;
}

__device__ __forceinline__ float evalChan16(const ChanDesc& d,
                                            const _Float16* __restrict__ srow,
                                            const _Float16* __restrict__ vrow,
                                            float mix, float u0, float u1, float u2) {
  if (d.path == 0) return (float)srow[d.off] * mix;
  if (d.path == 2) return (float)vrow[d.off] * mix;
  float uo = d.i == 0 ? u0 : (d.i == 1 ? u1 : u2);
  if (d.path == 3) return (float)srow[d.off] * uo * mix;
  float dd = (float)vrow[d.off] * u0 + (float)vrow[d.off + 1] * u1 + (float)vrow[d.off + 2] * u2;
  if (d.path == 1) return dd * mix;
  return 1.22474487139f * (uo * dd - (float)vrow[d.off + d.i] * 0.33333333333f) * mix;
}

__device__ __forceinline__ void radialEmb(float x, float y, float z, bool valid,
                                          float* emb, float* u0, float* u1, float* u2) {
  float r2 = x * x + y * y + z * z;
  float r = sqrtf(r2);
  float invr = 1.f / fmaxf(r, 1e-12f);
  *u0 = x * invr; *u1 = y * invr; *u2 = z * invr;
  float env = 0.f;
  if (r < 1.f) {
    float r3 = r * r2;
    float r6 = r3 * r3;
    env = 1.f + r6 * (-28.f + (48.f - 21.f * r) * r);
  }
  float coef = 1.41421356237f * invr * env;
  if (!valid || r == 0.f) coef = 0.f;
  float ph = 3.14159265358979323846f * r;
  float s1 = __sinf(ph), c1 = __cosf(ph);
  float twc = 2.f * c1;
  float sp = 0.f, sc = s1;
#pragma unroll
  for (int n = 0; n < NB; ++n) {  // sin(pi*n*r) via Chebyshev recurrence
    emb[n] = coef * sc;
    float sn = twc * sc - sp;
    sp = sc;
    sc = sn;
  }
}

// ============================ sort ============================

__global__ __launch_bounds__(256) void hist_kernel(const int* __restrict__ rcv,
                                                   int* __restrict__ hist, int E) {
  int e = blockIdx.x * 256 + threadIdx.x;
  if (e < E) atomicAdd(&hist[rcv[e]], 1);
}

__global__ __launch_bounds__(256) void scan1_kernel(const int* __restrict__ hist,
                                                    int* __restrict__ scanTmp,
                                                    int* __restrict__ bsum, int N) {
  __shared__ int sh[256];
  int t = threadIdx.x;
  int i = blockIdx.x * 256 + t;
  sh[t] = (i < N) ? hist[i] : 0;
  __syncthreads();
#pragma unroll
  for (int off = 1; off < 256; off <<= 1) {
    int x = (t >= off) ? sh[t - off] : 0;
    __syncthreads();
    sh[t] += x;
    __syncthreads();
  }
  if (i < N) scanTmp[i] = sh[t];
  if (t == 255) bsum[blockIdx.x] = sh[255];
}

__global__ __launch_bounds__(256) void scan2_kernel(int* __restrict__ bsum, int nb) {
  __shared__ int sh[256];
  int t = threadIdx.x;
  sh[t] = (t < nb) ? bsum[t] : 0;
  __syncthreads();
#pragma unroll
  for (int off = 1; off < 256; off <<= 1) {
    int x = (t >= off) ? sh[t - off] : 0;
    __syncthreads();
    sh[t] += x;
    __syncthreads();
  }
  int excl = (t == 0) ? 0 : sh[t - 1];
  if (t < nb) bsum[t] = excl;
}

__global__ __launch_bounds__(256) void scan3_kernel(const int* __restrict__ scanTmp,
                                                    const int* __restrict__ bsum,
                                                    const int* __restrict__ hist,
                                                    int* __restrict__ offs,
                                                    int* __restrict__ cursor, int N) {
  int i = blockIdx.x * 256 + threadIdx.x;
  if (i < N) {
    int incl = scanTmp[i] + bsum[blockIdx.x];
    offs[i + 1] = incl;
    cursor[i] = incl - hist[i];
    if (i == 0) offs[0] = 0;
  }
}

__global__ __launch_bounds__(256) void reorder_kernel(const int* __restrict__ rcv,
                                                      int* __restrict__ cursor,
                                                      int* __restrict__ sortedE, int E) {
  int e = blockIdx.x * 256 + threadIdx.x;
  if (e < E) {
    int pos = atomicAdd(&cursor[rcv[e]], 1);
    sortedE[pos] = e;
  }
}

__global__ __launch_bounds__(256) void reorderInv_kernel(const int* __restrict__ rcv,
                                                         int* __restrict__ cursor,
                                                         int* __restrict__ invPos, int E) {
  int e = blockIdx.x * 256 + threadIdx.x;
  if (e < E) {
    int pos = atomicAdd(&cursor[rcv[e]], 1);
    invPos[e] = pos;
  }
}

// ==================== weight / node dtype conversion ====================

__global__ __launch_bounds__(256) void wconv2_kernel(const float* __restrict__ W1,
                                                     const float* __restrict__ W2,
                                                     _Float16* __restrict__ W1T,
                                                     _Float16* __restrict__ W2T) {
  int i = blockIdx.x * 256 + threadIdx.x;
  if (i < 4096) {
    int k = i >> 6, n = i & 63;
    W1T[n * 64 + k] = (_Float16)(W1[k * 64 + n] * 0.125f);
  } else if (i < 4096 + 7168) {
    int j = i - 4096;
    int k = j / 112, n = j - k * 112;
    W2T[n * 64 + k] = (_Float16)(W2[k * 112 + n] * 0.125f);
  }
}

__global__ __launch_bounds__(256) void nodeconv_kernel(const float* __restrict__ ns,
                                                       const float* __restrict__ nv,
                                                       _Float16* __restrict__ s16,
                                                       _Float16* __restrict__ v16, int N) {
  int i = blockIdx.x * 256 + threadIdx.x;
  int ts = N * N_S;
  int tv = N * N_V * 3;
  if (i < ts) s16[i] = (_Float16)ns[i];
  else if (i < ts + tv) v16[i - ts] = (_Float16)nv[i - ts];
}

// ==================== MFMA radial MLP -> receiver-sorted rows ====================

__global__ __launch_bounds__(256, 4) void mlp_mfma_sorted_kernel(
    const float* __restrict__ vec,
    const float* __restrict__ W0,
    const _Float16* __restrict__ W1T,   // [n=64][k=64], *0.125
    const _Float16* __restrict__ W2T,   // [n=112][k=64], *0.125
    const int* __restrict__ senders,
    const int* __restrict__ invPos,
    _Float16* __restrict__ mixS,        // [E][MROW]
    int E) {
  __shared__ __align__(16) _Float16 hbuf[4 * 64 * 72];
  const int lane = threadIdx.x & 63;
  const int wave = threadIdx.x >> 6;
  const int gbase = blockIdx.x * 256 + wave * 64;
  _Float16* hb = hbuf + wave * (64 * 72);

  const int m15 = lane & 15;
  const int q = lane >> 4;

  // ---- phase 1: lane = edge; emb -> h1 -> LDS row; aux -> pad halves ----
  {
    int e = gbase + lane;
    bool valid = e < E;
    float x = 0.f, y = 0.f, z = 0.f;
    int snd = 0;
    if (valid) {
      const float* vp = vec + 3 * (size_t)e;
      x = vp[0]; y = vp[1]; z = vp[2];
      snd = senders[e];
    }
    float emb[NB], u0, u1, u2;
    radialEmb(x, y, z, valid, emb, &u0, &u1, &u2);
    for (int kg = 0; kg < 8; ++kg) {
      half8 pk;
#pragma unroll
      for (int kk = 0; kk < 8; ++kk) {
        int k = kg * 8 + kk;
        float a = 0.f;
#pragma unroll
        for (int n = 0; n < NB; ++n) a = fmaf(emb[n], W0[n * HH + k], a);
        pk[kk] = (_Float16)swishf(a * 0.35355339059f);
      }
      *(half8*)(hb + lane * 72 + kg * 8) = pk;
    }
    float* auxp = (float*)(hb + lane * 72 + 64);
    auxp[0] = u0; auxp[1] = u1; auxp[2] = u2;
    ((int*)auxp)[3] = snd;
  }

  // ---- W1 B-fragments ----
  half8 bW1[4][2];
#pragma unroll
  for (int nt = 0; nt < 4; ++nt)
#pragma unroll
    for (int q2 = 0; q2 < 2; ++q2)
      bW1[nt][q2] = *(const half8*)(W1T + (nt * 16 + m15) * 64 + q2 * 32 + q * 8);

  // ---- layer 1: MFMA, swish, write h2 in place ----
#pragma unroll
  for (int t = 0; t < 4; ++t) {
    half8 a0 = *(const half8*)(hb + (t * 16 + m15) * 72 + q * 8);
    half8 a1 = *(const half8*)(hb + (t * 16 + m15) * 72 + 32 + q * 8);
#pragma unroll
    for (int nt = 0; nt < 4; ++nt) {
      f32x4 d = {0.f, 0.f, 0.f, 0.f};
      d = __builtin_amdgcn_mfma_f32_16x16x32_f16(a0, bW1[nt][0], d, 0, 0, 0);
      d = __builtin_amdgcn_mfma_f32_16x16x32_f16(a1, bW1[nt][1], d, 0, 0, 0);
#pragma unroll
      for (int r = 0; r < 4; ++r)
        hb[(t * 16 + q * 4 + r) * 72 + nt * 16 + m15] = (_Float16)swishf(d[r]);
    }
  }

  // ---- layer 2 A-fragments in regs ----
  half8 A2[4][2];
#pragma unroll
  for (int t = 0; t < 4; ++t)
#pragma unroll
    for (int q2 = 0; q2 < 2; ++q2)
      A2[t][q2] = *(const half8*)(hb + (t * 16 + m15) * 72 + q2 * 32 + q * 8);

  // ---- layer 2 half 0: N-tiles 0..3 (ch 0..63) ----
  for (int nl = 0; nl < 4; ++nl) {
    half8 b0 = *(const half8*)(W2T + (nl * 16 + m15) * 64 + q * 8);
    half8 b1 = *(const half8*)(W2T + (nl * 16 + m15) * 64 + 32 + q * 8);
#pragma unroll
    for (int t = 0; t < 4; ++t) {
      f32x4 d = {0.f, 0.f, 0.f, 0.f};
      d = __builtin_amdgcn_mfma_f32_16x16x32_f16(A2[t][0], b0, d, 0, 0, 0);
      d = __builtin_amdgcn_mfma_f32_16x16x32_f16(A2[t][1], b1, d, 0, 0, 0);
#pragma unroll
      for (int r = 0; r < 4; ++r)
        hb[(t * 16 + q * 4 + r) * 72 + nl * 16 + m15] = (_Float16)d[r];
    }
  }
  for (int it = 0; it < 8; ++it) {
    int c = it * 64 + lane;
    int el = c >> 3, p = c & 7;
    int e = gbase + el;
    half8 v = *(const half8*)(hb + el * 72 + p * 8);
    if (e < E) {
      int pos = invPos[e];
      *(half8*)(mixS + (size_t)pos * MROW + p * 8) = v;
    }
  }

  // ---- layer 2 half 1: N-tiles 4..6 (ch 64..111) ----
  for (int nl = 0; nl < 3; ++nl) {
    int ntg = 4 + nl;
    half8 b0 = *(const half8*)(W2T + (ntg * 16 + m15) * 64 + q * 8);
    half8 b1 = *(const half8*)(W2T + (ntg * 16 + m15) * 64 + 32 + q * 8);
#pragma unroll
    for (int t = 0; t < 4; ++t) {
      f32x4 d = {0.f, 0.f, 0.f, 0.f};
      d = __builtin_amdgcn_mfma_f32_16x16x32_f16(A2[t][0], b0, d, 0, 0, 0);
      d = __builtin_amdgcn_mfma_f32_16x16x32_f16(A2[t][1], b1, d, 0, 0, 0);
#pragma unroll
      for (int r = 0; r < 4; ++r)
        hb[(t * 16 + q * 4 + r) * 72 + nl * 16 + m15] = (_Float16)d[r];
    }
  }
  for (int it = 0; it < 7; ++it) {
    int c = it * 64 + lane;
    int el = (int)(((unsigned)c * 9363u) >> 16);  // c/7 for c<448
    int p = c - el * 7;
    int e = gbase + el;
    half8 v = *(const half8*)(hb + el * 72 + (p < 6 ? p * 8 : 64));
    if (e < E) {
      int pos = invPos[e];
      *(half8*)(mixS + (size_t)pos * MROW + 64 + p * 8) = v;  // p==6 -> aux at 112
    }
  }
}

// ==================== LDS-staged sorted gather ====================
// Block = 4 consecutive receivers. Per <=64-edge chunk: (1) 256 threads stream the
// contiguous mix rows into LDS (coalesced, fully parallel); (2) 256 threads gather
// the fp16 node rows in parallel (10 x 16-B chunks/edge spread over block);
// (3) each wave accumulates its receiver's edges from LDS. Maximizes MLP vs the
// serial chain of the round-6 kernel.
__global__ __launch_bounds__(256) void gather_lds_kernel(
    const _Float16* __restrict__ mixS,
    const _Float16* __restrict__ s16,
    const _Float16* __restrict__ v16,
    const int* __restrict__ offs,
    float* __restrict__ out, int N) {
  __shared__ __align__(16) _Float16 mixLds[GCAP * MROW];  // 15360 B
  __shared__ __align__(16) _Float16 nodeLds[GCAP * 80];   // 10240 B

  const int tid = threadIdx.x;
  const int lane = tid & 63;
  const int wave = tid >> 6;
  const int wid0 = blockIdx.x * 4;

  const int e0 = offs[wid0];
  const int e4 = offs[min(wid0 + 4, N)];
  const int wid = wid0 + wave;
  const int sw = offs[min(wid, N)];
  const int ew = offs[min(wid + 1, N)];

  ChanDesc d[4];
#pragma unroll
  for (int tb = 0; tb < 4; ++tb) mkDesc(tb * 64 + lane, d[tb]);

  float acc[4] = {0.f, 0.f, 0.f, 0.f};

  for (int c0 = e0; c0 < e4; c0 += GCAP) {
    const int cnt = min(GCAP, e4 - c0);
    // stage 1: mix rows, coalesced 16-B chunks
    for (int ch = tid; ch < cnt * 15; ch += 256) {
      int row = ch / 15, part = ch - row * 15;
      *(half8*)(mixLds + row * MROW + part * 8) =
          *(const half8*)(mixS + (size_t)(c0 + row) * MROW + part * 8);
    }
    __syncthreads();
    // stage 2: node rows, parallel random 16-B chunks (s:4, v:6 per edge)
    for (int ch = tid; ch < cnt * 10; ch += 256) {
      int row = ch / 10, part = ch - row * 10;
      int snd = ((const int*)(mixLds + row * MROW + 112))[3];
      const _Float16* src = (part < 4)
          ? s16 + (size_t)snd * N_S + part * 8
          : v16 + (size_t)snd * (N_V * 3) + (part - 4) * 8;
      *(half8*)(nodeLds + row * 80 + (part < 4 ? part * 8 : 32 + (part - 4) * 8)) =
          *(const half8*)src;
    }
    __syncthreads();
    // stage 3: wave-local accumulation from LDS
    const int jlo = max(sw - c0, 0);
    const int jhi = min(ew - c0, cnt);
    for (int j = jlo; j < jhi; ++j) {
      const _Float16* row = mixLds + j * MROW;
      const float* aux = (const float*)(row + 112);
      float u0 = aux[0], u1 = aux[1], u2 = aux[2];
      const _Float16* srow = nodeLds + j * 80;
      const _Float16* vrow = srow + 32;
#pragma unroll
      for (int tb = 0; tb < 4; ++tb) {
        if (d[tb].path >= 0) {
          float m = (float)row[d[tb].mixI];
          acc[tb] += evalChan16(d[tb], srow, vrow, m, u0, u1, u2);
        }
      }
    }
    __syncthreads();
  }

  if (wid < N) {
    float* orow = out + (size_t)wid * ROW;
#pragma unroll
    for (int tb = 0; tb < 4; ++tb) {
      int t = tb * 64 + lane;
      if (t < ROW) orow[t] = 0.25f * acc[tb];
    }
  }
}

// ==================== tier B: round-5 kernels (edge-ordered mix) ====================

__global__ __launch_bounds__(256, 4) void mlp_mfma_kernel(
    const float* __restrict__ vec,
    const float* __restrict__ W0,
    const _Float16* __restrict__ W1T,
    const _Float16* __restrict__ W2T,
    __half* __restrict__ mixOut, int E) {
  __shared__ __align__(16) _Float16 hbuf[4 * 64 * 72];
  const int lane = threadIdx.x & 63;
  const int wave = threadIdx.x >> 6;
  const int gbase = blockIdx.x * 256 + wave * 64;
  _Float16* hb = hbuf + wave * (64 * 72);
  const int m15 = lane & 15;
  const int q = lane >> 4;

  {
    int e = gbase + lane;
    bool valid = e < E;
    float x = 0.f, y = 0.f, z = 0.f;
    if (valid) {
      const float* vp = vec + 3 * (size_t)e;
      x = vp[0]; y = vp[1]; z = vp[2];
    }
    float emb[NB], u0, u1, u2;
    radialEmb(x, y, z, valid, emb, &u0, &u1, &u2);
    for (int kg = 0; kg < 8; ++kg) {
      half8 pk;
#pragma unroll
      for (int kk = 0; kk < 8; ++kk) {
        int k = kg * 8 + kk;
        float a = 0.f;
#pragma unroll
        for (int n = 0; n < NB; ++n) a = fmaf(emb[n], W0[n * HH + k], a);
        pk[kk] = (_Float16)swishf(a * 0.35355339059f);
      }
      *(half8*)(hb + lane * 72 + kg * 8) = pk;
    }
  }

  half8 bW1[4][2];
#pragma unroll
  for (int nt = 0; nt < 4; ++nt)
#pragma unroll
    for (int q2 = 0; q2 < 2; ++q2)
      bW1[nt][q2] = *(const half8*)(W1T + (nt * 16 + m15) * 64 + q2 * 32 + q * 8);

#pragma unroll
  for (int t = 0; t < 4; ++t) {
    half8 a0 = *(const half8*)(hb + (t * 16 + m15) * 72 + q * 8);
    half8 a1 = *(const half8*)(hb + (t * 16 + m15) * 72 + 32 + q * 8);
#pragma unroll
    for (int nt = 0; nt < 4; ++nt) {
      f32x4 d = {0.f, 0.f, 0.f, 0.f};
      d = __builtin_amdgcn_mfma_f32_16x16x32_f16(a0, bW1[nt][0], d, 0, 0, 0);
      d = __builtin_amdgcn_mfma_f32_16x16x32_f16(a1, bW1[nt][1], d, 0, 0, 0);
#pragma unroll
      for (int r = 0; r < 4; ++r)
        hb[(t * 16 + q * 4 + r) * 72 + nt * 16 + m15] = (_Float16)swishf(d[r]);
    }
  }

  half8 A2[4][2];
#pragma unroll
  for (int t = 0; t < 4; ++t)
#pragma unroll
    for (int q2 = 0; q2 < 2; ++q2)
      A2[t][q2] = *(const half8*)(hb + (t * 16 + m15) * 72 + q2 * 32 + q * 8);

  for (int hf = 0; hf < 2; ++hf) {
    const int ntCount = hf ? 3 : 4;
    for (int nl = 0; nl < ntCount; ++nl) {
      int ntg = hf * 4 + nl;
      half8 b0 = *(const half8*)(W2T + (ntg * 16 + m15) * 64 + q * 8);
      half8 b1 = *(const half8*)(W2T + (ntg * 16 + m15) * 64 + 32 + q * 8);
#pragma unroll
      for (int t = 0; t < 4; ++t) {
        f32x4 d = {0.f, 0.f, 0.f, 0.f};
        d = __builtin_amdgcn_mfma_f32_16x16x32_f16(A2[t][0], b0, d, 0, 0, 0);
        d = __builtin_amdgcn_mfma_f32_16x16x32_f16(A2[t][1], b1, d, 0, 0, 0);
#pragma unroll
        for (int r = 0; r < 4; ++r)
          hb[(t * 16 + q * 4 + r) * 72 + nl * 16 + m15] = (_Float16)d[r];
      }
    }
    if (hf == 0) {
      for (int it = 0; it < 8; ++it) {
        int c = it * 64 + lane;
        int el = c >> 3, p = c & 7;
        int e = gbase + el;
        half8 v = *(const half8*)(hb + el * 72 + p * 8);
        if (e < E) *(half8*)((_Float16*)mixOut + (size_t)e * NIR + p * 8) = v;
      }
    } else {
      for (int it = 0; it < 6; ++it) {
        int c = it * 64 + lane;
        int el = (int)(((unsigned)c * 43691u) >> 18);
        int p = c - el * 6;
        int e = gbase + el;
        half8 v = *(const half8*)(hb + el * 72 + p * 8);
        if (e < E) *(half8*)((_Float16*)mixOut + (size_t)e * NIR + 64 + p * 8) = v;
      }
    }
  }
}

__global__ __launch_bounds__(256) void gather_kernel(
    const float* __restrict__ vec,
    const float* __restrict__ nodes_s,
    const float* __restrict__ nodes_v,
    const int* __restrict__ senders,
    const int* __restrict__ offs,
    const int* __restrict__ sortedE,
    const __half* __restrict__ mix,
    float* __restrict__ out, int N) {
  int wid = blockIdx.x * 4 + (threadIdx.x >> 6);
  int lane = threadIdx.x & 63;
  if (wid >= N) return;

  ChanDesc d[4];
#pragma unroll
  for (int tb = 0; tb < 4; ++tb) mkDesc(tb * 64 + lane, d[tb]);

  float acc[4] = {0.f, 0.f, 0.f, 0.f};
  int s0 = offs[wid], s1 = offs[wid + 1];

  for (int i = s0; i < s1; ++i) {
    int e = __builtin_amdgcn_readfirstlane(sortedE[i]);
    int snd = __builtin_amdgcn_readfirstlane(senders[e]);
    const float* vp = vec + 3 * (size_t)e;
    float x = vp[0], y = vp[1], z = vp[2];
    float r = sqrtf(x * x + y * y + z * z);
    float invr = 1.f / fmaxf(r, 1e-12f);
    float u0 = x * invr, u1 = y * invr, u2 = z * invr;
    const float* srow = nodes_s + (size_t)snd * N_S;
    const float* vrow = nodes_v + (size_t)snd * (N_V * 3);
    const __half* mrow = mix + (size_t)e * NIR;
#pragma unroll
    for (int tb = 0; tb < 4; ++tb) {
      if (d[tb].path >= 0) {
        float m = __half2float(mrow[d[tb].mixI]);
        acc[tb] += evalChan(d[tb], srow, vrow, m, u0, u1, u2);
      }
    }
  }

  float* orow = out + (size_t)wid * ROW;
#pragma unroll
  for (int tb = 0; tb < 4; ++tb) {
    int t = tb * 64 + lane;
    if (t < ROW) orow[t] = 0.25f * acc[tb];
  }
}

// ==================== tier C fallback: atomic edge kernel ====================

__global__ __launch_bounds__(64) void edge_kernel(
    const float* __restrict__ vec,
    const float* __restrict__ nodes_s,
    const float* __restrict__ nodes_v,
    const int* __restrict__ senders,
    const int* __restrict__ receivers,
    const float* __restrict__ W0f,
    const float* __restrict__ W1f,
    const float* __restrict__ W2f,
    float* __restrict__ out, int E) {
  __shared__ float hLds[HH * 64];
  __shared__ float uLds[64 * 3];
  __shared__ int sLds[64];
  __shared__ int rLds[64];
  __half* mixLds = reinterpret_cast<__half*>(hLds);

  const int lane = threadIdx.x;
  const int base = blockIdx.x * 64;
  const int eg = base + lane;
  const bool valid = eg < E;

  float emb[NB];
  {
    float x = 0.f, y = 0.f, z = 0.f;
    int snd = 0, rcv = 0;
    if (valid) {
      const float* vp = vec + 3 * (size_t)eg;
      x = vp[0]; y = vp[1]; z = vp[2];
      snd = senders[eg];
      rcv = receivers[eg];
    }
    float u0, u1, u2;
    radialEmb(x, y, z, valid, emb, &u0, &u1, &u2);
    uLds[lane * 3 + 0] = u0;
    uLds[lane * 3 + 1] = u1;
    uLds[lane * 3 + 2] = u2;
    sLds[lane] = snd;
    rLds[lane] = rcv;
  }

  for (int j0 = 0; j0 < HH; j0 += 8) {
    float a[8];
#pragma unroll
    for (int jj = 0; jj < 8; ++jj) a[jj] = 0.f;
#pragma unroll
    for (int k = 0; k < NB; ++k) {
      const float* wrow = W0f + k * HH + j0;
      float ek = emb[k];
#pragma unroll
      for (int jj = 0; jj < 8; ++jj) a[jj] = fmaf(ek, wrow[jj], a[jj]);
    }
#pragma unroll
    for (int jj = 0; jj < 8; ++jj)
      hLds[(j0 + jj) * 64 + lane] = swishf(a[jj] * 0.35355339059f);
  }
  __syncthreads();

  float h2[HH];
#pragma unroll
  for (int j = 0; j < HH; ++j) h2[j] = 0.f;
  for (int k = 0; k < HH; ++k) {
    float hk = hLds[k * 64 + lane];
    const float* wrow = W1f + k * HH;
#pragma unroll
    for (int j = 0; j < HH; ++j) h2[j] = fmaf(hk, wrow[j], h2[j]);
  }
#pragma unroll
  for (int j = 0; j < HH; ++j) h2[j] = swishf(h2[j] * 0.125f);
  __syncthreads();

  for (int m0 = 0; m0 < NIR; m0 += 4) {
    float a0 = 0.f, a1 = 0.f, a2 = 0.f, a3 = 0.f;
#pragma unroll
    for (int k = 0; k < HH; ++k) {
      const float* wrow = W2f + k * NIR + m0;
      float hk = h2[k];
      a0 = fmaf(hk, wrow[0], a0);
      a1 = fmaf(hk, wrow[1], a1);
      a2 = fmaf(hk, wrow[2], a2);
      a3 = fmaf(hk, wrow[3], a3);
    }
    mixLds[lane * NIR + m0 + 0] = __float2half_rn(a0 * 0.125f);
    mixLds[lane * NIR + m0 + 1] = __float2half_rn(a1 * 0.125f);
    mixLds[lane * NIR + m0 + 2] = __float2half_rn(a2 * 0.125f);
    mixLds[lane * NIR + m0 + 3] = __float2half_rn(a3 * 0.125f);
  }
  __syncthreads();

  ChanDesc d[4];
#pragma unroll
  for (int tb = 0; tb < 4; ++tb) mkDesc(tb * 64 + lane, d[tb]);

  const int cnt = min(64, E - base);
  for (int e = 0; e < cnt; ++e) {
    int snd = sLds[e], rcv = rLds[e];
    float u0 = uLds[e * 3 + 0], u1 = uLds[e * 3 + 1], u2 = uLds[e * 3 + 2];
    const float* srow = nodes_s + (size_t)snd * N_S;
    const float* vrow = nodes_v + (size_t)snd * (N_V * 3);
    const __half* mrow = mixLds + e * NIR;
    float* orow = out + (size_t)rcv * ROW;
#pragma unroll
    for (int tb = 0; tb < 4; ++tb) {
      if (d[tb].path >= 0) {
        float m = __half2float(mrow[d[tb].mixI]);
        float val = evalChan(d[tb], srow, vrow, m, u0, u1, u2);
        unsafeAtomicAdd(orow + tb * 64 + lane, 0.25f * val);
      }
    }
  }
}

// ===============================================================================

extern "C" void kernel_launch(void* const* d_in, const int* in_sizes, int n_in,
                              void* d_out, int out_size, void* d_ws, size_t ws_size,
                              hipStream_t stream) {
  const float* vec = (const float*)d_in[0];
  const float* ns = (const float*)d_in[1];
  const float* nv = (const float*)d_in[2];
  const float* w0 = (const float*)d_in[3];
  const float* w1 = (const float*)d_in[4];
  const float* w2 = (const float*)d_in[5];
  const int* snd = (const int*)d_in[6];
  const int* rcv = (const int*)d_in[7];
  float* out = (float*)d_out;

  const int E = in_sizes[6];
  const int N = in_sizes[1] / N_S;
  const int nb = (N + 255) / 256;
  const int eb = (E + 255) / 256;

  // ---- tier A layout: sorted mix rows + fp16 nodes ----
  {
    char* p = (char*)d_ws;
    _Float16* mixS = (_Float16*)p; p += (size_t)E * MROW * sizeof(_Float16);
    int* hist = (int*)p;           p += (size_t)N * 4;
    int* scanTmp = (int*)p;        p += (size_t)N * 4;
    int* offs = (int*)p;           p += ((size_t)N + 1) * 4;
    int* cursor = (int*)p;         p += (size_t)N * 4;
    int* bsum = (int*)p;           p += 256 * 4;
    int* invPos = (int*)p;         p += (size_t)E * 4;
    p = (char*)(((uintptr_t)p + 15) & ~(uintptr_t)15);
    _Float16* W1T = (_Float16*)p;  p += 4096 * sizeof(_Float16);
    _Float16* W2T = (_Float16*)p;  p += 7168 * sizeof(_Float16);
    _Float16* s16 = (_Float16*)p;  p += (size_t)N * N_S * sizeof(_Float16);
    _Float16* v16 = (_Float16*)p;  p += (size_t)N * N_V * 3 * sizeof(_Float16);
    size_t needA = (size_t)(p - (char*)d_ws);

    if (needA <= ws_size && nb <= 256) {
      hipMemsetAsync(hist, 0, (size_t)N * 4, stream);
      hist_kernel<<<eb, 256, 0, stream>>>(rcv, hist, E);
      scan1_kernel<<<nb, 256, 0, stream>>>(hist, scanTmp, bsum, N);
      scan2_kernel<<<1, 256, 0, stream>>>(bsum, nb);
      scan3_kernel<<<nb, 256, 0, stream>>>(scanTmp, bsum, hist, offs, cursor, N);
      reorderInv_kernel<<<eb, 256, 0, stream>>>(rcv, cursor, invPos, E);
      wconv2_kernel<<<44, 256, 0, stream>>>(w1, w2, W1T, W2T);
      nodeconv_kernel<<<(N * 80 + 255) / 256, 256, 0, stream>>>(ns, nv, s16, v16, N);
      mlp_mfma_sorted_kernel<<<eb, 256, 0, stream>>>(vec, w0, W1T, W2T, snd, invPos, mixS, E);
      gather_lds_kernel<<<(N + 3) / 4, 256, 0, stream>>>(mixS, s16, v16, offs, out, N);
      return;
    }
  }

  // ---- tier B layout: round-5 path ----
  {
    char* p = (char*)d_ws;
    __half* mixW = (__half*)p;     p += (size_t)E * NIR * sizeof(__half);
    int* hist = (int*)p;           p += (size_t)N * 4;
    int* scanTmp = (int*)p;        p += (size_t)N * 4;
    int* offs = (int*)p;           p += ((size_t)N + 1) * 4;
    int* cursor = (int*)p;         p += (size_t)N * 4;
    int* bsum = (int*)p;           p += 256 * 4;
    int* sortedE = (int*)p;        p += (size_t)E * 4;
    p = (char*)(((uintptr_t)p + 15) & ~(uintptr_t)15);
    _Float16* W1T = (_Float16*)p;  p += 4096 * sizeof(_Float16);
    _Float16* W2T = (_Float16*)p;  p += 7168 * sizeof(_Float16);
    size_t needB = (size_t)(p - (char*)d_ws);

    if (needB <= ws_size && nb <= 256) {
      hipMemsetAsync(hist, 0, (size_t)N * 4, stream);
      hist_kernel<<<eb, 256, 0, stream>>>(rcv, hist, E);
      scan1_kernel<<<nb, 256, 0, stream>>>(hist, scanTmp, bsum, N);
      scan2_kernel<<<1, 256, 0, stream>>>(bsum, nb);
      scan3_kernel<<<nb, 256, 0, stream>>>(scanTmp, bsum, hist, offs, cursor, N);
      reorder_kernel<<<eb, 256, 0, stream>>>(rcv, cursor, sortedE, E);
      wconv2_kernel<<<44, 256, 0, stream>>>(w1, w2, W1T, W2T);
      mlp_mfma_kernel<<<eb, 256, 0, stream>>>(vec, w0, W1T, W2T, mixW, E);
      gather_kernel<<<(N + 3) / 4, 256, 0, stream>>>(vec, ns, nv, snd, offs, sortedE, mixW, out, N);
      return;
    }
  }

  // ---- tier C: atomic fallback ----
  hipMemsetAsync(d_out, 0, (size_t)out_size * sizeof(float), stream);
  edge_kernel<<<(E + 63) / 64, 64, 0, stream>>>(vec, ns, nv, snd, rcv, w0, w1, w2, out, E);
}

// Round 8
// 559.578 us; speedup vs baseline: 1.1820x; 1.0038x over previous
//
#include <hip/hip_runtime.h>
#include <hip/hip_fp16.h>

#define N_S 32
#define N_V 16
#define NB 8
#define HH 64
#define NIR 112
#define ROW 240   // 48 scalar + 64*3 vector output channels
#define MROW 120  // tier-B mix row: 112 fp16 mix + {u0,u1,u2 fp32, sender int}
#define GCAP 64   // tier-B edges staged per gather chunk

typedef _Float16 half8 __attribute__((ext_vector_type(8)));
typedef _Float16 half4v __attribute__((ext_vector_type(4)));
typedef float f32x4 __attribute__((ext_vector_type(4)));

#define H8F(arr, idx) ((float)arr[(idx) >> 3][(idx) & 7])

__device__ __forceinline__ float swishf(float x) {
  return x / (1.f + __expf(-x));
}

struct ChanDesc { int path, off, mixI, i; };

__device__ __forceinline__ void mkDesc(int t, ChanDesc& d) {
  if (t < 32) { d.path = 0; d.off = t; d.mixI = t; d.i = 0; }
  else if (t < 48) { d.path = 1; d.off = 3 * (t - 32); d.mixI = t; d.i = 0; }
  else if (t < ROW) {
    int q = t - 48, c = q / 3, i = q - 3 * c;
    d.mixI = 48 + c;
    if (c < 16) { d.path = 2; d.off = q; d.i = 0; }
    else if (c < 48) { d.path = 3; d.off = c - 16; d.i = i; }
    else { d.path = 4; d.off = 3 * (c - 48); d.i = i; }
  } else { d.path = -1; d.off = 0; d.mixI = 0; d.i = 0; }
}

__device__ __forceinline__ float evalChan(const ChanDesc& d,
                                          const float* __restrict__ srow,
                                          const float* __restrict__ vrow,
                                          float mix, float u0, float u1, float u2) {
  if (d.path < 0) return 0.f;
  if (d.path == 0) return srow[d.off] * mix;
  if (d.path == 2) return vrow[d.off] * mix;
  float uo = d.i == 0 ? u0 : (d.i == 1 ? u1 : u2);
  if (d.path == 3) return srow[d.off] * uo * mix;
  float dd = vrow[d.off] * u0 + vrow[d.off + 1] * u1 + vrow[d.off + 2] * u2;
  if (d.path == 1) return dd * mix;
  return 1.22474487139f * (uo * dd - vrow[d.off + d.i] * 0.33333333333f) * mix;
}

__device__ __forceinline__ float evalChan16(const ChanDesc& d,
                                            const _Float16* __restrict__ srow,
                                            const _Float16* __restrict__ vrow,
                                            float mix, float u0, float u1, float u2) {
  if (d.path == 0) return (float)srow[d.off] * mix;
  if (d.path == 2) return (float)vrow[d.off] * mix;
  float uo = d.i == 0 ? u0 : (d.i == 1 ? u1 : u2);
  if (d.path == 3) return (float)srow[d.off] * uo * mix;
  float dd = (float)vrow[d.off] * u0 + (float)vrow[d.off + 1] * u1 + (float)vrow[d.off + 2] * u2;
  if (d.path == 1) return dd * mix;
  return 1.22474487139f * (uo * dd - (float)vrow[d.off + d.i] * 0.33333333333f) * mix;
}

__device__ __forceinline__ void radialEmb(float x, float y, float z, bool valid,
                                          float* emb, float* u0, float* u1, float* u2) {
  float r2 = x * x + y * y + z * z;
  float r = sqrtf(r2);
  float invr = 1.f / fmaxf(r, 1e-12f);
  *u0 = x * invr; *u1 = y * invr; *u2 = z * invr;
  float env = 0.f;
  if (r < 1.f) {
    float r3 = r * r2;
    float r6 = r3 * r3;
    env = 1.f + r6 * (-28.f + (48.f - 21.f * r) * r);
  }
  float coef = 1.41421356237f * invr * env;
  if (!valid || r == 0.f) coef = 0.f;
  float ph = 3.14159265358979323846f * r;
  float s1 = __sinf(ph), c1 = __cosf(ph);
  float twc = 2.f * c1;
  float sp = 0.f, sc = s1;
#pragma unroll
  for (int n = 0; n < NB; ++n) {  // sin(pi*n*r) via Chebyshev recurrence
    emb[n] = coef * sc;
    float sn = twc * sc - sp;
    sp = sc;
    sc = sn;
  }
}

// ============================ sort ============================

__global__ __launch_bounds__(256) void hist_kernel(const int* __restrict__ rcv,
                                                   int* __restrict__ hist, int E) {
  int e = blockIdx.x * 256 + threadIdx.x;
  if (e < E) atomicAdd(&hist[rcv[e]], 1);
}

__global__ __launch_bounds__(256) void scan1_kernel(const int* __restrict__ hist,
                                                    int* __restrict__ scanTmp,
                                                    int* __restrict__ bsum, int N) {
  __shared__ int sh[256];
  int t = threadIdx.x;
  int i = blockIdx.x * 256 + t;
  sh[t] = (i < N) ? hist[i] : 0;
  __syncthreads();
#pragma unroll
  for (int off = 1; off < 256; off <<= 1) {
    int x = (t >= off) ? sh[t - off] : 0;
    __syncthreads();
    sh[t] += x;
    __syncthreads();
  }
  if (i < N) scanTmp[i] = sh[t];
  if (t == 255) bsum[blockIdx.x] = sh[255];
}

__global__ __launch_bounds__(256) void scan2_kernel(int* __restrict__ bsum, int nb) {
  __shared__ int sh[256];
  int t = threadIdx.x;
  sh[t] = (t < nb) ? bsum[t] : 0;
  __syncthreads();
#pragma unroll
  for (int off = 1; off < 256; off <<= 1) {
    int x = (t >= off) ? sh[t - off] : 0;
    __syncthreads();
    sh[t] += x;
    __syncthreads();
  }
  int excl = (t == 0) ? 0 : sh[t - 1];
  if (t < nb) bsum[t] = excl;
}

__global__ __launch_bounds__(256) void scan3_kernel(const int* __restrict__ scanTmp,
                                                    const int* __restrict__ bsum,
                                                    const int* __restrict__ hist,
                                                    int* __restrict__ offs,
                                                    int* __restrict__ cursor, int N) {
  int i = blockIdx.x * 256 + threadIdx.x;
  if (i < N) {
    int incl = scanTmp[i] + bsum[blockIdx.x];
    offs[i + 1] = incl;
    cursor[i] = incl - hist[i];
    if (i == 0) offs[0] = 0;
  }
}

__global__ __launch_bounds__(256) void reorderInv_kernel(const int* __restrict__ rcv,
                                                         int* __restrict__ cursor,
                                                         int* __restrict__ invPos, int E) {
  int e = blockIdx.x * 256 + threadIdx.x;
  if (e < E) {
    int pos = atomicAdd(&cursor[rcv[e]], 1);
    invPos[e] = pos;
  }
}

// ==================== prep: weights fp16-T (scales folded) + nodes fp16 ====================

__global__ __launch_bounds__(256) void prep_kernel(const float* __restrict__ W1,
                                                   const float* __restrict__ W2,
                                                   const float* __restrict__ ns,
                                                   const float* __restrict__ nv,
                                                   _Float16* __restrict__ W1T,
                                                   _Float16* __restrict__ W2T,
                                                   _Float16* __restrict__ s16,
                                                   _Float16* __restrict__ v16, int N) {
  int i = blockIdx.x * 256 + threadIdx.x;
  int ts = N * N_S;
  int tv = N * N_V * 3;
  if (i < ts) s16[i] = (_Float16)ns[i];
  else if (i < ts + tv) v16[i - ts] = (_Float16)nv[i - ts];
  else if (i < ts + tv + 4096) {
    int j = i - ts - tv;
    int k = j >> 6, n = j & 63;
    W1T[n * 64 + k] = (_Float16)(W1[k * 64 + n] * 0.125f);
  } else if (i < ts + tv + 4096 + 7168) {
    int j = i - ts - tv - 4096;
    int k = j / 112, n = j - k * 112;
    W2T[n * 64 + k] = (_Float16)(W2[k * 112 + n] * 0.125f);
  }
}

// ==================== tier A: fused MLP + message eval -> sorted fp16 rows ====================
// Block = 4 waves; wave owns 64 edges + private 9216-B LDS slice, no barriers.
// After MFMA layer-2 each lane reads ITS edge's mix row from LDS and evaluates all
// 240 message channels (16 evals/wave-instr vs ~10 in the wave-per-edge gather),
// storing half8 chunks to msgS[invPos[e]] (dense 480-B rows, receiver-sorted).
__global__ __launch_bounds__(256, 2) void mlp_msg_kernel(
    const float* __restrict__ vec,
    const float* __restrict__ W0,
    const _Float16* __restrict__ W1T,   // [n=64][k=64], *0.125
    const _Float16* __restrict__ W2T,   // [n=112][k=64], *0.125
    const int* __restrict__ senders,
    const int* __restrict__ invPos,
    const _Float16* __restrict__ s16,
    const _Float16* __restrict__ v16,
    _Float16* __restrict__ msgS,        // [E][240]
    int E) {
  __shared__ __align__(16) _Float16 hbuf[4 * 64 * 72];
  const int lane = threadIdx.x & 63;
  const int wave = threadIdx.x >> 6;
  const int gbase = blockIdx.x * 256 + wave * 64;
  _Float16* hb = hbuf + wave * (64 * 72);

  const int m15 = lane & 15;
  const int q = lane >> 4;

  int e = gbase + lane;
  bool valid = e < E;
  float x = 0.f, y = 0.f, z = 0.f;
  int snd = 0, pos = 0;
  if (valid) {
    const float* vp = vec + 3 * (size_t)e;
    x = vp[0]; y = vp[1]; z = vp[2];
    snd = senders[e];
    pos = invPos[e];
  }
  float emb[NB], u0, u1, u2;
  radialEmb(x, y, z, valid, emb, &u0, &u1, &u2);

  // ---- phase 1: h1 -> LDS row [edge][64] ----
  for (int kg = 0; kg < 8; ++kg) {
    half8 pk;
#pragma unroll
    for (int kk = 0; kk < 8; ++kk) {
      int k = kg * 8 + kk;
      float a = 0.f;
#pragma unroll
      for (int n = 0; n < NB; ++n) a = fmaf(emb[n], W0[n * HH + k], a);
      pk[kk] = (_Float16)swishf(a * 0.35355339059f);
    }
    *(half8*)(hb + lane * 72 + kg * 8) = pk;
  }

  // ---- sender node rows (fp16), issued early to hide latency behind MFMAs ----
  half8 ss[4], vv[6];
  {
    const _Float16* sp = s16 + (size_t)snd * N_S;
    const _Float16* vp16 = v16 + (size_t)snd * (N_V * 3);
#pragma unroll
    for (int k = 0; k < 4; ++k) ss[k] = *(const half8*)(sp + k * 8);
#pragma unroll
    for (int k = 0; k < 6; ++k) vv[k] = *(const half8*)(vp16 + k * 8);
  }

  // ---- layer 1: MFMA, swish, h2 in place ----
  {
    half8 bW1[4][2];
#pragma unroll
    for (int nt = 0; nt < 4; ++nt)
#pragma unroll
      for (int q2 = 0; q2 < 2; ++q2)
        bW1[nt][q2] = *(const half8*)(W1T + (nt * 16 + m15) * 64 + q2 * 32 + q * 8);
#pragma unroll
    for (int t = 0; t < 4; ++t) {
      half8 a0 = *(const half8*)(hb + (t * 16 + m15) * 72 + q * 8);
      half8 a1 = *(const half8*)(hb + (t * 16 + m15) * 72 + 32 + q * 8);
#pragma unroll
      for (int nt = 0; nt < 4; ++nt) {
        f32x4 d = {0.f, 0.f, 0.f, 0.f};
        d = __builtin_amdgcn_mfma_f32_16x16x32_f16(a0, bW1[nt][0], d, 0, 0, 0);
        d = __builtin_amdgcn_mfma_f32_16x16x32_f16(a1, bW1[nt][1], d, 0, 0, 0);
#pragma unroll
        for (int r = 0; r < 4; ++r)
          hb[(t * 16 + q * 4 + r) * 72 + nt * 16 + m15] = (_Float16)swishf(d[r]);
      }
    }
  }

  // ---- layer 2 A-fragments ----
  half8 A2[4][2];
#pragma unroll
  for (int t = 0; t < 4; ++t)
#pragma unroll
    for (int q2 = 0; q2 < 2; ++q2)
      A2[t][q2] = *(const half8*)(hb + (t * 16 + m15) * 72 + q2 * 32 + q * 8);

  // ---- dot products d[j] = v_j . u ----
  float d16[16];
#pragma unroll
  for (int j = 0; j < 16; ++j)
    d16[j] = H8F(vv, 3 * j) * u0 + H8F(vv, 3 * j + 1) * u1 + H8F(vv, 3 * j + 2) * u2;

  _Float16* orow = msgS + (size_t)pos * ROW;

  // ---- layer 2 half 0 (mix ch 0..63) ----
  for (int nl = 0; nl < 4; ++nl) {
    half8 b0 = *(const half8*)(W2T + (nl * 16 + m15) * 64 + q * 8);
    half8 b1 = *(const half8*)(W2T + (nl * 16 + m15) * 64 + 32 + q * 8);
#pragma unroll
    for (int t = 0; t < 4; ++t) {
      f32x4 d = {0.f, 0.f, 0.f, 0.f};
      d = __builtin_amdgcn_mfma_f32_16x16x32_f16(A2[t][0], b0, d, 0, 0, 0);
      d = __builtin_amdgcn_mfma_f32_16x16x32_f16(A2[t][1], b1, d, 0, 0, 0);
#pragma unroll
      for (int r = 0; r < 4; ++r)
        hb[(t * 16 + q * 4 + r) * 72 + nl * 16 + m15] = (_Float16)d[r];
    }
  }
  half8 m0[8];
#pragma unroll
  for (int k = 0; k < 8; ++k) m0[k] = *(const half8*)(hb + lane * 72 + k * 8);

  // ---- layer 2 half 1 (mix ch 64..111 -> hb cols 0..47); reads above precede writes ----
  for (int nl = 0; nl < 3; ++nl) {
    int ntg = 4 + nl;
    half8 b0 = *(const half8*)(W2T + (ntg * 16 + m15) * 64 + q * 8);
    half8 b1 = *(const half8*)(W2T + (ntg * 16 + m15) * 64 + 32 + q * 8);
#pragma unroll
    for (int t = 0; t < 4; ++t) {
      f32x4 d = {0.f, 0.f, 0.f, 0.f};
      d = __builtin_amdgcn_mfma_f32_16x16x32_f16(A2[t][0], b0, d, 0, 0, 0);
      d = __builtin_amdgcn_mfma_f32_16x16x32_f16(A2[t][1], b1, d, 0, 0, 0);
#pragma unroll
      for (int r = 0; r < 4; ++r)
        hb[(t * 16 + q * 4 + r) * 72 + nl * 16 + m15] = (_Float16)d[r];
    }
  }

  // ---- eval + store message ch 0..95 (needs mix half0 only) ----
#pragma unroll
  for (int ck = 0; ck < 12; ++ck) {
    half8 outv;
#pragma unroll
    for (int jj = 0; jj < 8; ++jj) {
      const int t = ck * 8 + jj;
      float val;
      if (t < 32) {
        val = H8F(m0, t) * H8F(ss, t);
      } else if (t < 48) {
        val = H8F(m0, t) * d16[t - 32];
      } else {
        const int c = (t - 48) / 3;
        val = H8F(m0, 48 + c) * H8F(vv, t - 48);
      }
      outv[jj] = (_Float16)val;
    }
    if (valid) *(half8*)(orow + ck * 8) = outv;
  }

  // ---- read mix half1, eval + store ch 96..239 ----
  half8 m1[6];
#pragma unroll
  for (int k = 0; k < 6; ++k) m1[k] = *(const half8*)(hb + lane * 72 + k * 8);
#pragma unroll
  for (int ck = 0; ck < 18; ++ck) {
    half8 outv;
#pragma unroll
    for (int jj = 0; jj < 8; ++jj) {
      const int t = 96 + ck * 8 + jj;
      const int c = (t - 48) / 3;
      const int i = (t - 48) % 3;
      const float uo = (i == 0) ? u0 : ((i == 1) ? u1 : u2);
      const float m = H8F(m1, c - 16);  // mixI = 48+c, stored at col (48+c)-64
      float val;
      if (c < 48) {
        val = m * H8F(ss, c - 16) * uo;
      } else {
        val = 1.22474487139f * (uo * d16[c - 48] - H8F(vv, t - 192) * 0.33333333333f) * m;
      }
      outv[jj] = (_Float16)val;
    }
    if (valid) *(half8*)(orow + 96 + ck * 8) = outv;
  }
}

// ==================== tier A gather: pure streaming segmented sum ====================

__global__ __launch_bounds__(256) void gather_stream_kernel(
    const _Float16* __restrict__ msgS,
    const int* __restrict__ offs,
    float* __restrict__ out, int N) {
  int wid = blockIdx.x * 4 + (threadIdx.x >> 6);
  int lane = threadIdx.x & 63;
  if (wid >= N) return;
  int s0 = __builtin_amdgcn_readfirstlane(offs[wid]);
  int s1 = __builtin_amdgcn_readfirstlane(offs[wid + 1]);
  const bool act = lane < 60;

  float a0 = 0.f, a1 = 0.f, a2 = 0.f, a3 = 0.f;
  const _Float16* base = msgS + (size_t)s0 * ROW + lane * 4;
  const int n = s1 - s0;
  int j = 0;
  for (; j + 2 <= n; j += 2) {
    half4v va = {0, 0, 0, 0}, vb = {0, 0, 0, 0};
    if (act) {
      va = *(const half4v*)(base + (size_t)j * ROW);
      vb = *(const half4v*)(base + (size_t)(j + 1) * ROW);
    }
    a0 += (float)va[0] + (float)vb[0];
    a1 += (float)va[1] + (float)vb[1];
    a2 += (float)va[2] + (float)vb[2];
    a3 += (float)va[3] + (float)vb[3];
  }
  if (j < n && act) {
    half4v va = *(const half4v*)(base + (size_t)j * ROW);
    a0 += (float)va[0]; a1 += (float)va[1]; a2 += (float)va[2]; a3 += (float)va[3];
  }
  if (act) {
    float4 o = make_float4(0.25f * a0, 0.25f * a1, 0.25f * a2, 0.25f * a3);
    *(float4*)(out + (size_t)wid * ROW + lane * 4) = o;
  }
}

// ==================== tier B: round-7 verified path ====================

__global__ __launch_bounds__(256, 4) void mlp_mfma_sorted_kernel(
    const float* __restrict__ vec,
    const float* __restrict__ W0,
    const _Float16* __restrict__ W1T,
    const _Float16* __restrict__ W2T,
    const int* __restrict__ senders,
    const int* __restrict__ invPos,
    _Float16* __restrict__ mixS,        // [E][MROW]
    int E) {
  __shared__ __align__(16) _Float16 hbuf[4 * 64 * 72];
  const int lane = threadIdx.x & 63;
  const int wave = threadIdx.x >> 6;
  const int gbase = blockIdx.x * 256 + wave * 64;
  _Float16* hb = hbuf + wave * (64 * 72);

  const int m15 = lane & 15;
  const int q = lane >> 4;

  {
    int e = gbase + lane;
    bool valid = e < E;
    float x = 0.f, y = 0.f, z = 0.f;
    int snd = 0;
    if (valid) {
      const float* vp = vec + 3 * (size_t)e;
      x = vp[0]; y = vp[1]; z = vp[2];
      snd = senders[e];
    }
    float emb[NB], u0, u1, u2;
    radialEmb(x, y, z, valid, emb, &u0, &u1, &u2);
    for (int kg = 0; kg < 8; ++kg) {
      half8 pk;
#pragma unroll
      for (int kk = 0; kk < 8; ++kk) {
        int k = kg * 8 + kk;
        float a = 0.f;
#pragma unroll
        for (int n = 0; n < NB; ++n) a = fmaf(emb[n], W0[n * HH + k], a);
        pk[kk] = (_Float16)swishf(a * 0.35355339059f);
      }
      *(half8*)(hb + lane * 72 + kg * 8) = pk;
    }
    float* auxp = (float*)(hb + lane * 72 + 64);
    auxp[0] = u0; auxp[1] = u1; auxp[2] = u2;
    ((int*)auxp)[3] = snd;
  }

  half8 bW1[4][2];
#pragma unroll
  for (int nt = 0; nt < 4; ++nt)
#pragma unroll
    for (int q2 = 0; q2 < 2; ++q2)
      bW1[nt][q2] = *(const half8*)(W1T + (nt * 16 + m15) * 64 + q2 * 32 + q * 8);

#pragma unroll
  for (int t = 0; t < 4; ++t) {
    half8 a0 = *(const half8*)(hb + (t * 16 + m15) * 72 + q * 8);
    half8 a1 = *(const half8*)(hb + (t * 16 + m15) * 72 + 32 + q * 8);
#pragma unroll
    for (int nt = 0; nt < 4; ++nt) {
      f32x4 d = {0.f, 0.f, 0.f, 0.f};
      d = __builtin_amdgcn_mfma_f32_16x16x32_f16(a0, bW1[nt][0], d, 0, 0, 0);
      d = __builtin_amdgcn_mfma_f32_16x16x32_f16(a1, bW1[nt][1], d, 0, 0, 0);
#pragma unroll
      for (int r = 0; r < 4; ++r)
        hb[(t * 16 + q * 4 + r) * 72 + nt * 16 + m15] = (_Float16)swishf(d[r]);
    }
  }

  half8 A2[4][2];
#pragma unroll
  for (int t = 0; t < 4; ++t)
#pragma unroll
    for (int q2 = 0; q2 < 2; ++q2)
      A2[t][q2] = *(const half8*)(hb + (t * 16 + m15) * 72 + q2 * 32 + q * 8);

  for (int nl = 0; nl < 4; ++nl) {
    half8 b0 = *(const half8*)(W2T + (nl * 16 + m15) * 64 + q * 8);
    half8 b1 = *(const half8*)(W2T + (nl * 16 + m15) * 64 + 32 + q * 8);
#pragma unroll
    for (int t = 0; t < 4; ++t) {
      f32x4 d = {0.f, 0.f, 0.f, 0.f};
      d = __builtin_amdgcn_mfma_f32_16x16x32_f16(A2[t][0], b0, d, 0, 0, 0);
      d = __builtin_amdgcn_mfma_f32_16x16x32_f16(A2[t][1], b1, d, 0, 0, 0);
#pragma unroll
      for (int r = 0; r < 4; ++r)
        hb[(t * 16 + q * 4 + r) * 72 + nl * 16 + m15] = (_Float16)d[r];
    }
  }
  for (int it = 0; it < 8; ++it) {
    int c = it * 64 + lane;
    int el = c >> 3, p = c & 7;
    int e = gbase + el;
    half8 v = *(const half8*)(hb + el * 72 + p * 8);
    if (e < E) {
      int pos = invPos[e];
      *(half8*)(mixS + (size_t)pos * MROW + p * 8) = v;
    }
  }

  for (int nl = 0; nl < 3; ++nl) {
    int ntg = 4 + nl;
    half8 b0 = *(const half8*)(W2T + (ntg * 16 + m15) * 64 + q * 8);
    half8 b1 = *(const half8*)(W2T + (ntg * 16 + m15) * 64 + 32 + q * 8);
#pragma unroll
    for (int t = 0; t < 4; ++t) {
      f32x4 d = {0.f, 0.f, 0.f, 0.f};
      d = __builtin_amdgcn_mfma_f32_16x16x32_f16(A2[t][0], b0, d, 0, 0, 0);
      d = __builtin_amdgcn_mfma_f32_16x16x32_f16(A2[t][1], b1, d, 0, 0, 0);
#pragma unroll
      for (int r = 0; r < 4; ++r)
        hb[(t * 16 + q * 4 + r) * 72 + nl * 16 + m15] = (_Float16)d[r];
    }
  }
  for (int it = 0; it < 7; ++it) {
    int c = it * 64 + lane;
    int el = (int)(((unsigned)c * 9363u) >> 16);  // c/7 for c<448
    int p = c - el * 7;
    int e = gbase + el;
    half8 v = *(const half8*)(hb + el * 72 + (p < 6 ? p * 8 : 64));
    if (e < E) {
      int pos = invPos[e];
      *(half8*)(mixS + (size_t)pos * MROW + 64 + p * 8) = v;
    }
  }
}

__global__ __launch_bounds__(256) void gather_lds_kernel(
    const _Float16* __restrict__ mixS,
    const _Float16* __restrict__ s16,
    const _Float16* __restrict__ v16,
    const int* __restrict__ offs,
    float* __restrict__ out, int N) {
  __shared__ __align__(16) _Float16 mixLds[GCAP * MROW];
  __shared__ __align__(16) _Float16 nodeLds[GCAP * 80];

  const int tid = threadIdx.x;
  const int lane = tid & 63;
  const int wave = tid >> 6;
  const int wid0 = blockIdx.x * 4;

  const int e0 = offs[wid0];
  const int e4 = offs[min(wid0 + 4, N)];
  const int wid = wid0 + wave;
  const int sw = offs[min(wid, N)];
  const int ew = offs[min(wid + 1, N)];

  ChanDesc d[4];
#pragma unroll
  for (int tb = 0; tb < 4; ++tb) mkDesc(tb * 64 + lane, d[tb]);

  float acc[4] = {0.f, 0.f, 0.f, 0.f};

  for (int c0 = e0; c0 < e4; c0 += GCAP) {
    const int cnt = min(GCAP, e4 - c0);
    for (int ch = tid; ch < cnt * 15; ch += 256) {
      int row = ch / 15, part = ch - row * 15;
      *(half8*)(mixLds + row * MROW + part * 8) =
          *(const half8*)(mixS + (size_t)(c0 + row) * MROW + part * 8);
    }
    __syncthreads();
    for (int ch = tid; ch < cnt * 10; ch += 256) {
      int row = ch / 10, part = ch - row * 10;
      int snd = ((const int*)(mixLds + row * MROW + 112))[3];
      const _Float16* src = (part < 4)
          ? s16 + (size_t)snd * N_S + part * 8
          : v16 + (size_t)snd * (N_V * 3) + (part - 4) * 8;
      *(half8*)(nodeLds + row * 80 + (part < 4 ? part * 8 : 32 + (part - 4) * 8)) =
          *(const half8*)src;
    }
    __syncthreads();
    const int jlo = max(sw - c0, 0);
    const int jhi = min(ew - c0, cnt);
    for (int j = jlo; j < jhi; ++j) {
      const _Float16* row = mixLds + j * MROW;
      const float* aux = (const float*)(row + 112);
      float u0 = aux[0], u1 = aux[1], u2 = aux[2];
      const _Float16* srow = nodeLds + j * 80;
      const _Float16* vrow = srow + 32;
#pragma unroll
      for (int tb = 0; tb < 4; ++tb) {
        if (d[tb].path >= 0) {
          float m = (float)row[d[tb].mixI];
          acc[tb] += evalChan16(d[tb], srow, vrow, m, u0, u1, u2);
        }
      }
    }
    __syncthreads();
  }

  if (wid < N) {
    float* orow = out + (size_t)wid * ROW;
#pragma unroll
    for (int tb = 0; tb < 4; ++tb) {
      int t = tb * 64 + lane;
      if (t < ROW) orow[t] = 0.25f * acc[tb];
    }
  }
}

// ==================== tier D fallback: atomic edge kernel ====================

__global__ __launch_bounds__(64) void edge_kernel(
    const float* __restrict__ vec,
    const float* __restrict__ nodes_s,
    const float* __restrict__ nodes_v,
    const int* __restrict__ senders,
    const int* __restrict__ receivers,
    const float* __restrict__ W0f,
    const float* __restrict__ W1f,
    const float* __restrict__ W2f,
    float* __restrict__ out, int E) {
  __shared__ float hLds[HH * 64];
  __shared__ float uLds[64 * 3];
  __shared__ int sLds[64];
  __shared__ int rLds[64];
  __half* mixLds = reinterpret_cast<__half*>(hLds);

  const int lane = threadIdx.x;
  const int base = blockIdx.x * 64;
  const int eg = base + lane;
  const bool valid = eg < E;

  float emb[NB];
  {
    float x = 0.f, y = 0.f, z = 0.f;
    int snd = 0, rcv = 0;
    if (valid) {
      const float* vp = vec + 3 * (size_t)eg;
      x = vp[0]; y = vp[1]; z = vp[2];
      snd = senders[eg];
      rcv = receivers[eg];
    }
    float u0, u1, u2;
    radialEmb(x, y, z, valid, emb, &u0, &u1, &u2);
    uLds[lane * 3 + 0] = u0;
    uLds[lane * 3 + 1] = u1;
    uLds[lane * 3 + 2] = u2;
    sLds[lane] = snd;
    rLds[lane] = rcv;
  }

  for (int j0 = 0; j0 < HH; j0 += 8) {
    float a[8];
#pragma unroll
    for (int jj = 0; jj < 8; ++jj) a[jj] = 0.f;
#pragma unroll
    for (int k = 0; k < NB; ++k) {
      const float* wrow = W0f + k * HH + j0;
      float ek = emb[k];
#pragma unroll
      for (int jj = 0; jj < 8; ++jj) a[jj] = fmaf(ek, wrow[jj], a[jj]);
    }
#pragma unroll
    for (int jj = 0; jj < 8; ++jj)
      hLds[(j0 + jj) * 64 + lane] = swishf(a[jj] * 0.35355339059f);
  }
  __syncthreads();

  float h2[HH];
#pragma unroll
  for (int j = 0; j < HH; ++j) h2[j] = 0.f;
  for (int k = 0; k < HH; ++k) {
    float hk = hLds[k * 64 + lane];
    const float* wrow = W1f + k * HH;
#pragma unroll
    for (int j = 0; j < HH; ++j) h2[j] = fmaf(hk, wrow[j], h2[j]);
  }
#pragma unroll
  for (int j = 0; j < HH; ++j) h2[j] = swishf(h2[j] * 0.125f);
  __syncthreads();

  for (int m0 = 0; m0 < NIR; m0 += 4) {
    float a0 = 0.f, a1 = 0.f, a2 = 0.f, a3 = 0.f;
#pragma unroll
    for (int k = 0; k < HH; ++k) {
      const float* wrow = W2f + k * NIR + m0;
      float hk = h2[k];
      a0 = fmaf(hk, wrow[0], a0);
      a1 = fmaf(hk, wrow[1], a1);
      a2 = fmaf(hk, wrow[2], a2);
      a3 = fmaf(hk, wrow[3], a3);
    }
    mixLds[lane * NIR + m0 + 0] = __float2half_rn(a0 * 0.125f);
    mixLds[lane * NIR + m0 + 1] = __float2half_rn(a1 * 0.125f);
    mixLds[lane * NIR + m0 + 2] = __float2half_rn(a2 * 0.125f);
    mixLds[lane * NIR + m0 + 3] = __float2half_rn(a3 * 0.125f);
  }
  __syncthreads();

  ChanDesc d[4];
#pragma unroll
  for (int tb = 0; tb < 4; ++tb) mkDesc(tb * 64 + lane, d[tb]);

  const int cnt = min(64, E - base);
  for (int e = 0; e < cnt; ++e) {
    int snd = sLds[e], rcv = rLds[e];
    float u0 = uLds[e * 3 + 0], u1 = uLds[e * 3 + 1], u2 = uLds[e * 3 + 2];
    const float* srow = nodes_s + (size_t)snd * N_S;
    const float* vrow = nodes_v + (size_t)snd * (N_V * 3);
    const __half* mrow = mixLds + e * NIR;
    float* orow = out + (size_t)rcv * ROW;
#pragma unroll
    for (int tb = 0; tb < 4; ++tb) {
      if (d[tb].path >= 0) {
        float m = __half2float(mrow[d[tb].mixI]);
        float val = evalChan(d[tb], srow, vrow, m, u0, u1, u2);
        unsafeAtomicAdd(orow + tb * 64 + lane, 0.25f * val);
      }
    }
  }
}

// ===============================================================================

extern "C" void kernel_launch(void* const* d_in, const int* in_sizes, int n_in,
                              void* d_out, int out_size, void* d_ws, size_t ws_size,
                              hipStream_t stream) {
  const float* vec = (const float*)d_in[0];
  const float* ns = (const float*)d_in[1];
  const float* nv = (const float*)d_in[2];
  const float* w0 = (const float*)d_in[3];
  const float* w1 = (const float*)d_in[4];
  const float* w2 = (const float*)d_in[5];
  const int* snd = (const int*)d_in[6];
  const int* rcv = (const int*)d_in[7];
  float* out = (float*)d_out;

  const int E = in_sizes[6];
  const int N = in_sizes[1] / N_S;
  const int nb = (N + 255) / 256;
  const int eb = (E + 255) / 256;
  const int prepElems = N * (N_S + N_V * 3) + 4096 + 7168;

  // ---- tier A: fused message materialization + streaming gather ----
  {
    char* p = (char*)d_ws;
    _Float16* msgS = (_Float16*)p;  p += (size_t)E * ROW * sizeof(_Float16);
    int* hist = (int*)p;            p += (size_t)N * 4;
    int* scanTmp = (int*)p;         p += (size_t)N * 4;
    int* offs = (int*)p;            p += ((size_t)N + 1) * 4;
    int* cursor = (int*)p;          p += (size_t)N * 4;
    int* bsum = (int*)p;            p += 256 * 4;
    int* invPos = (int*)p;          p += (size_t)E * 4;
    p = (char*)(((uintptr_t)p + 15) & ~(uintptr_t)15);
    _Float16* W1T = (_Float16*)p;   p += 4096 * sizeof(_Float16);
    _Float16* W2T = (_Float16*)p;   p += 7168 * sizeof(_Float16);
    _Float16* s16 = (_Float16*)p;   p += (size_t)N * N_S * sizeof(_Float16);
    _Float16* v16 = (_Float16*)p;   p += (size_t)N * N_V * 3 * sizeof(_Float16);
    size_t needA = (size_t)(p - (char*)d_ws);

    if (needA <= ws_size && nb <= 256) {
      hipMemsetAsync(hist, 0, (size_t)N * 4, stream);
      hist_kernel<<<eb, 256, 0, stream>>>(rcv, hist, E);
      scan1_kernel<<<nb, 256, 0, stream>>>(hist, scanTmp, bsum, N);
      scan2_kernel<<<1, 256, 0, stream>>>(bsum, nb);
      scan3_kernel<<<nb, 256, 0, stream>>>(scanTmp, bsum, hist, offs, cursor, N);
      reorderInv_kernel<<<eb, 256, 0, stream>>>(rcv, cursor, invPos, E);
      prep_kernel<<<(prepElems + 255) / 256, 256, 0, stream>>>(w1, w2, ns, nv, W1T, W2T, s16, v16, N);
      mlp_msg_kernel<<<eb, 256, 0, stream>>>(vec, w0, W1T, W2T, snd, invPos, s16, v16, msgS, E);
      gather_stream_kernel<<<(N + 3) / 4, 256, 0, stream>>>(msgS, offs, out, N);
      return;
    }
  }

  // ---- tier B: round-7 verified path ----
  {
    char* p = (char*)d_ws;
    _Float16* mixS = (_Float16*)p;  p += (size_t)E * MROW * sizeof(_Float16);
    int* hist = (int*)p;            p += (size_t)N * 4;
    int* scanTmp = (int*)p;         p += (size_t)N * 4;
    int* offs = (int*)p;            p += ((size_t)N + 1) * 4;
    int* cursor = (int*)p;          p += (size_t)N * 4;
    int* bsum = (int*)p;            p += 256 * 4;
    int* invPos = (int*)p;          p += (size_t)E * 4;
    p = (char*)(((uintptr_t)p + 15) & ~(uintptr_t)15);
    _Float16* W1T = (_Float16*)p;   p += 4096 * sizeof(_Float16);
    _Float16* W2T = (_Float16*)p;   p += 7168 * sizeof(_Float16);
    _Float16* s16 = (_Float16*)p;   p += (size_t)N * N_S * sizeof(_Float16);
    _Float16* v16 = (_Float16*)p;   p += (size_t)N * N_V * 3 * sizeof(_Float16);
    size_t needB = (size_t)(p - (char*)d_ws);

    if (needB <= ws_size && nb <= 256) {
      hipMemsetAsync(hist, 0, (size_t)N * 4, stream);
      hist_kernel<<<eb, 256, 0, stream>>>(rcv, hist, E);
      scan1_kernel<<<nb, 256, 0, stream>>>(hist, scanTmp, bsum, N);
      scan2_kernel<<<1, 256, 0, stream>>>(bsum, nb);
      scan3_kernel<<<nb, 256, 0, stream>>>(scanTmp, bsum, hist, offs, cursor, N);
      reorderInv_kernel<<<eb, 256, 0, stream>>>(rcv, cursor, invPos, E);
      prep_kernel<<<(prepElems + 255) / 256, 256, 0, stream>>>(w1, w2, ns, nv, W1T, W2T, s16, v16, N);
      mlp_mfma_sorted_kernel<<<eb, 256, 0, stream>>>(vec, w0, W1T, W2T, snd, invPos, mixS, E);
      gather_lds_kernel<<<(N + 3) / 4, 256, 0, stream>>>(mixS, s16, v16, offs, out, N);
      return;
    }
  }

  // ---- tier D: atomic fallback ----
  hipMemsetAsync(d_out, 0, (size_t)out_size * sizeof(float), stream);
  edge_kernel<<<(E + 63) / 64, 64, 0, stream>>>(vec, ns, nv, snd, rcv, w0, w1, w2, out, E);
}